// Round 7
// baseline (5749.434 us; speedup 1.0000x reference)
//
#include <hip/hip_runtime.h>
#include <cstdint>
#include <cstddef>

#define B_ 4
#define N_ 16384
#define S_ 2048
#define K_ 32
#define D_ 64
#define C0_ 67
#define C3_ 256
#define P_ (B_*S_*K_)           // 262144 pixels
#define FEAT_OFF 24576          // B*3*S
#define SEED_OFF (24576 + B_*C3_*S_)

// ---------------------------------------------------------------------------
// FPS: R11. Evidence recap: R5-R8 flat (state lives in AGPRs -> ~80
// accvgpr moves/thread/iter, VALU-issue-bound, storage-insensitive);
// R10's 16-block exchange correct but sync ~4200cyc/iter (cold per-iter
// slots -> 13MB HBM poll traffic; 16-way stores+polls). R11 fixes both:
//  - 2 blocks/batch x 1024thr, 8 pts/thread = 32 state floats + temps
//    ~= 60 VGPR: fits UNDER the allocator's 8-waves/EU ceiling (<=64),
//    so state is register-resident -> scan issue halves, zero AGPR tax.
//  - pairwise exchange on HOT ping-pong slots (2/block, alternate by
//    it&1, 128B apart). Key u64 = tag(it+1)<<46 | val_bits<<14 |
//    (16383-idx): one word carries readiness+value+index -> relaxed
//    agent atomics suffice; u64 max = max-val-then-min-idx = reference
//    first-index argmax (vals >= 0 so ieee bits are monotone).
//    Ping-pong safety: block reaches it+2's store only after consuming
//    partner's it+1 store, which happens after partner's it-read.
// Distance chain bit-matched vs ref: d = fma(dz,dz, fma(dy,dy, dx*dx)).
// Scan split into two 4-chains (B's indices strictly larger per thread;
// "B only if strictly greater" keeps first-index semantics).
// ---------------------------------------------------------------------------
__global__ __launch_bounds__(1024) void fps_kernel(
    const float* __restrict__ xyz,
    const int* __restrict__ fps_start,
    unsigned long long* __restrict__ comm,
    int* __restrict__ fps_idx, float* __restrict__ new_xyz,
    float* __restrict__ d_out)
{
  const int blk = blockIdx.x;
  const int b = blk >> 1;            // batch
  const int g = blk & 1;             // half index within batch
  const int tid = threadIdx.x;
  const int lane = tid & 63;
  const int wid = tid >> 6;          // 0..15
  const float* __restrict__ xb = xyz + (size_t)b * 3 * N_;
  const int base = g * 8192;         // this block owns [base, base+8192)

  // 8 points/thread in named scalars: 24 coord + 8 dmin = 32 VGPRs state.
#define FDECL_(q) float px##q, py##q, pz##q, dm##q;
  FDECL_(0) FDECL_(1) FDECL_(2) FDECL_(3)
  FDECL_(4) FDECL_(5) FDECL_(6) FDECL_(7)
#define FINIT_(q) { int j = base + (q) * 1024 + tid;                         \
    px##q = xb[j]; py##q = xb[N_ + j]; pz##q = xb[2 * N_ + j];               \
    dm##q = 1e10f;                                                           \
    asm volatile("" : "+v"(px##q), "+v"(py##q), "+v"(pz##q)); }
  FINIT_(0) FINIT_(1) FINIT_(2) FINIT_(3)
  FINIT_(4) FINIT_(5) FINIT_(6) FINIT_(7)

  __shared__ unsigned long long s_part[16];
  __shared__ unsigned long long s_win;
  // Hot slots: 2 per block (ping-pong by it&1), 128B apart; partner's pair
  // adjacent. comm stride per block = 32 u64 (256B).
  unsigned long long* __restrict__ myslot = comm + (size_t)(b * 2 + g) * 32;
  unsigned long long* __restrict__ paslot = comm + (size_t)(b * 2 + (g ^ 1)) * 32;

  int cur = fps_start[b];
  for (int it = 0; it < S_; ++it) {
    int cs = __builtin_amdgcn_readfirstlane(cur);
    float cx = xb[cs], cy = xb[N_ + cs], cz = xb[2 * N_ + cs];
    if (g == 0 && tid == 0) {
      fps_idx[b * S_ + it] = cs;
      new_xyz[(b * S_ + it) * 3 + 0] = cx;
      new_xyz[(b * S_ + it) * 3 + 1] = cy;
      new_xyz[(b * S_ + it) * 3 + 2] = cz;
      d_out[(b * 3 + 0) * S_ + it] = cx;
      d_out[(b * 3 + 1) * S_ + it] = cy;
      d_out[(b * 3 + 2) * S_ + it] = cz;
    }
    if (it == S_ - 1) break;         // last argmax is never consumed

    // update dmin + local argmax: two chains (q<4, q>=4), merged after
    float bvA = -1e30f, bvB = -1e30f;
    int   iA = 0, iB = 4;
#define FSTEPA_(q) {                                                         \
    float dx = __fadd_rn(px##q, -cx);                                        \
    float dy = __fadd_rn(py##q, -cy);                                        \
    float dz = __fadd_rn(pz##q, -cz);                                        \
    float d = fmaf(dz, dz, fmaf(dy, dy, __fmul_rn(dx, dx)));                 \
    float m = fminf(dm##q, d); dm##q = m;                                    \
    bool gt = m > bvA;               /* strict: keeps earliest q on tie */   \
    bvA = fmaxf(bvA, m);                                                     \
    iA = gt ? (q) : iA; }
#define FSTEPB_(q) {                                                         \
    float dx = __fadd_rn(px##q, -cx);                                        \
    float dy = __fadd_rn(py##q, -cy);                                        \
    float dz = __fadd_rn(pz##q, -cz);                                        \
    float d = fmaf(dz, dz, fmaf(dy, dy, __fmul_rn(dx, dx)));                 \
    float m = fminf(dm##q, d); dm##q = m;                                    \
    bool gt = m > bvB;                                                       \
    bvB = fmaxf(bvB, m);                                                     \
    iB = gt ? (q) : iB; }
    FSTEPA_(0) FSTEPA_(1) FSTEPA_(2) FSTEPA_(3)
    FSTEPB_(4) FSTEPB_(5) FSTEPB_(6) FSTEPB_(7)
    // merge: B's indices all > A's for this thread; strict > keeps A on tie
    bool tb = bvB > bvA;
    float bv = tb ? bvB : bvA;
    int   bi = base + (tb ? iB : iA) * 1024 + tid;   // global point index

    // wave reduce (max val, min idx on tie)
#pragma unroll
    for (int off = 1; off < 64; off <<= 1) {
      float ov = __shfl_xor(bv, off, 64);
      int   oi = __shfl_xor(bi, off, 64);
      bool take = (ov > bv) || (ov == bv && oi < bi);
      bv = take ? ov : bv;
      bi = take ? oi : bi;
    }
    if (lane == 0)
      s_part[wid] = ((unsigned long long)__float_as_uint(bv) << 14) |
                    (unsigned long long)(16383 - bi);
    __syncthreads();
    if (wid == 0) {
      unsigned long long k = (lane < 16) ? s_part[lane] : 0ull;
#pragma unroll
      for (int off = 1; off < 16; off <<= 1) {
        unsigned long long ko = __shfl_xor(k, off, 64);
        k = (ko > k) ? ko : k;
      }
      if (lane == 0) {
        unsigned long long mykey =
            ((unsigned long long)(unsigned)(it + 1) << 46) | k;
        int sl = (it & 1) * 16;
        __hip_atomic_store(&myslot[sl], mykey, __ATOMIC_RELAXED,
                           __HIP_MEMORY_SCOPE_AGENT);
        unsigned long long pk;
        do {
          pk = __hip_atomic_load(&paslot[sl], __ATOMIC_RELAXED,
                                 __HIP_MEMORY_SCOPE_AGENT);
        } while ((pk >> 46) != (unsigned long long)(unsigned)(it + 1));
        s_win = (pk > mykey) ? pk : mykey;
      }
    }
    __syncthreads();
    cur = 16383 - (int)(s_win & 0x3FFFull);
  }
}

// seed_out[b][s] = (float)seed_inds[b][fps_idx[b][s]]
__global__ __launch_bounds__(256) void seed_gather_kernel(
    const int* __restrict__ seed_inds, const int* __restrict__ fps_idx,
    float* __restrict__ d_out)
{
  int i = blockIdx.x * 256 + threadIdx.x;      // 0 .. B*S-1
  if (i < B_ * S_) {
    int b = i >> 11;                           // i / S_
    d_out[SEED_OFF + i] = (float)seed_inds[(size_t)b * N_ + fps_idx[i]];
  }
}

// ---------------------------------------------------------------------------
// Ball query: one wave per centroid; first K in-ball indices ascending,
// pad with first hit.
// ---------------------------------------------------------------------------
__global__ __launch_bounds__(256) void ballquery_kernel(
    const float* __restrict__ xyz, const float* __restrict__ new_xyz,
    int* __restrict__ idxo)
{
  const int c = blockIdx.x * 4 + (threadIdx.x >> 6);
  const int lane = threadIdx.x & 63;
  const int b = c >> 11;
  const float* __restrict__ xb = xyz + (size_t)b * 3 * N_;
  float cx = new_xyz[c * 3 + 0], cy = new_xyz[c * 3 + 1], cz = new_xyz[c * 3 + 2];
  float css = __fadd_rn(__fadd_rn(__fmul_rn(cx, cx), __fmul_rn(cy, cy)),
                        __fmul_rn(cz, cz));
  const double rr = 0.3 * 0.3;
  int cnt = 0, first = -1;
  for (int base = 0; base < N_; base += 64) {
    int j = base + lane;
    float x = xb[j], y = xb[N_ + j], z = xb[2 * N_ + j];
    float pss = __fadd_rn(__fadd_rn(__fmul_rn(x, x), __fmul_rn(y, y)),
                          __fmul_rn(z, z));
    float dot = __fadd_rn(__fadd_rn(__fmul_rn(cx, x), __fmul_rn(cy, y)),
                          __fmul_rn(cz, z));
    float d = __fadd_rn(__fadd_rn(__fmul_rn(-2.f, dot), css), pss);
    bool in = (double)d <= rr;
    unsigned long long m = __ballot(in);
    if (m) {
      if (first < 0) first = base + (__ffsll((long long)m) - 1);
      int rank = (int)__popcll(m & ((1ull << lane) - 1ull));
      int pos = cnt + rank;
      if (in && pos < K_) idxo[(size_t)c * K_ + pos] = j;
      cnt += (int)__popcll(m);
      if (cnt >= K_) break;
    }
  }
  for (int p = cnt + lane; p < K_; p += 64) idxo[(size_t)c * K_ + p] = first;
}

// ---------------------------------------------------------------------------
// points (B,D,N) -> (B,N,D) (only used when ws_size permits).
// ---------------------------------------------------------------------------
__global__ __launch_bounds__(256) void transpose_pts_kernel(
    const float* __restrict__ pts, float* __restrict__ pts_t)
{
  __shared__ float tile[64][65];
  const int blk = blockIdx.x;
  const int b = blk >> 8;
  const int n0 = (blk & 255) * 64;
  const int tx = threadIdx.x & 63, ty = threadIdx.x >> 6;
#pragma unroll
  for (int r = 0; r < 16; ++r) {
    int d = r * 4 + ty;
    tile[d][tx] = pts[((size_t)b * D_ + d) * N_ + n0 + tx];
  }
  __syncthreads();
#pragma unroll
  for (int r = 0; r < 16; ++r) {
    int nl = r * 4 + ty;
    pts_t[((size_t)b * N_ + n0 + nl) * D_ + tx] = tile[tx][nl];
  }
}

__global__ void transpose_w_kernel(
    const float* __restrict__ W0, const float* __restrict__ W1,
    const float* __restrict__ W2, float* __restrict__ wt0,
    float* __restrict__ wt1, float* __restrict__ wt2)
{
  int i = blockIdx.x * 256 + threadIdx.x;
  if (i < 128 * 67) { int co = i / 67, ci = i % 67; wt0[ci * 128 + co] = W0[i]; }
  int i1 = i - 128 * 67;
  if (i1 >= 0 && i1 < 128 * 128) { int co = i1 >> 7, ci = i1 & 127; wt1[ci * 128 + co] = W1[i1]; }
  int i2 = i1 - 128 * 128;
  if (i2 >= 0 && i2 < 256 * 128) { int co = i2 >> 7, ci = i2 & 127; wt2[ci * 256 + co] = W2[i2]; }
}

// ---------------------------------------------------------------------------
// Shared device helpers for the recompute passes.
// ---------------------------------------------------------------------------
__device__ __forceinline__ void stage_x0(
    int gp0, int tid, const float* __restrict__ xyz,
    const float* __restrict__ pts, const float* __restrict__ pts_t, int use_pt,
    const float* __restrict__ new_xyz, const int* __restrict__ idxo,
    float* __restrict__ bufA)
{
  int pxl = tid >> 2, q = tid & 3;
  int gp = gp0 + pxl;
  int b = gp >> 16;
  int s = (gp >> 5) & (S_ - 1);
  int j = idxo[gp];
  if (use_pt) {
    const float* src = pts_t + ((size_t)b * N_ + j) * 64 + q * 16;
#pragma unroll
    for (int v = 0; v < 4; ++v) {
      float4 f = *(const float4*)(src + v * 4);
      int c = 3 + q * 16 + v * 4;
      bufA[(c + 0) * 72 + pxl] = f.x;
      bufA[(c + 1) * 72 + pxl] = f.y;
      bufA[(c + 2) * 72 + pxl] = f.z;
      bufA[(c + 3) * 72 + pxl] = f.w;
    }
  } else {
    const float* src = pts + ((size_t)b * D_ + q * 16) * N_ + j;
#pragma unroll
    for (int v = 0; v < 16; ++v)
      bufA[(3 + q * 16 + v) * 72 + pxl] = src[(size_t)v * N_];
  }
  if (q == 0) {
    const float* xb = xyz + (size_t)b * 3 * N_;
    int c3 = (b * S_ + s) * 3;
    bufA[0 * 72 + pxl] = xb[j] - new_xyz[c3 + 0];
    bufA[1 * 72 + pxl] = xb[N_ + j] - new_xyz[c3 + 1];
    bufA[2 * 72 + pxl] = xb[2 * N_ + j] - new_xyz[c3 + 2];
  }
}

// 8-cout conv micro-tile: acc[4 px][8 co] += buf[ci][pg*4..] * w[ci][cog*8..]
template<int CIN>
__device__ __forceinline__ void conv8(
    const float* __restrict__ buf, const float* __restrict__ wrow, int pg,
    float acc[4][8])
{
  for (int ci = 0; ci < CIN; ++ci) {
    float4 x4 = *(const float4*)&buf[ci * 72 + pg * 4];
    float4 wa = *(const float4*)&wrow[ci * 128];
    float4 wb = *(const float4*)&wrow[ci * 128 + 4];
    float xr[4] = {x4.x, x4.y, x4.z, x4.w};
    float wv[8] = {wa.x, wa.y, wa.z, wa.w, wb.x, wb.y, wb.z, wb.w};
#pragma unroll
    for (int i = 0; i < 4; ++i)
#pragma unroll
      for (int j = 0; j < 8; ++j) acc[i][j] = fmaf(xr[i], wv[j], acc[i][j]);
  }
}

// ---------------------------------------------------------------------------
// passA: conv0 stats only (no y0 store).
// ---------------------------------------------------------------------------
__global__ __launch_bounds__(256) void passA_kernel(
    const float* __restrict__ xyz, const float* __restrict__ pts,
    const float* __restrict__ pts_t, int use_pt,
    const float* __restrict__ new_xyz, const int* __restrict__ idxo,
    const float* __restrict__ wt0, const float* __restrict__ b0,
    float* __restrict__ gsum, float* __restrict__ gsq)
{
  __shared__ __align__(16) float bufA[C0_ * 72];
  __shared__ float s_sum[4][128], s_sq[4][128];
  const int tid = threadIdx.x;
  const int lane = tid & 63, wid = tid >> 6;
  const int cog = tid & 15, pg = tid >> 4;
  float bias[8];
#pragma unroll
  for (int j = 0; j < 8; ++j) bias[j] = b0[cog * 8 + j];
  float ssum[8], ssq[8];
#pragma unroll
  for (int j = 0; j < 8; ++j) { ssum[j] = 0.f; ssq[j] = 0.f; }

  for (int t = 0; t < 4; ++t) {
    const int gp0 = (blockIdx.x * 4 + t) * 64;
    __syncthreads();
    stage_x0(gp0, tid, xyz, pts, pts_t, use_pt, new_xyz, idxo, bufA);
    __syncthreads();
    float acc[4][8];
#pragma unroll
    for (int i = 0; i < 4; ++i)
#pragma unroll
      for (int j = 0; j < 8; ++j) acc[i][j] = 0.f;
    conv8<C0_>(bufA, wt0 + cog * 8, pg, acc);
#pragma unroll
    for (int i = 0; i < 4; ++i)
#pragma unroll
      for (int j = 0; j < 8; ++j) {
        float y = acc[i][j] + bias[j];
        ssum[j] += y;
        ssq[j] = fmaf(y, y, ssq[j]);
      }
  }
#pragma unroll
  for (int j = 0; j < 8; ++j) {
    float v = ssum[j];
    v += __shfl_xor(v, 16, 64); v += __shfl_xor(v, 32, 64);
    float q = ssq[j];
    q += __shfl_xor(q, 16, 64); q += __shfl_xor(q, 32, 64);
    if (lane < 16) { s_sum[wid][lane * 8 + j] = v; s_sq[wid][lane * 8 + j] = q; }
  }
  __syncthreads();
  if (tid < 128) {
    float v = s_sum[0][tid] + s_sum[1][tid] + s_sum[2][tid] + s_sum[3][tid];
    float q = s_sq[0][tid] + s_sq[1][tid] + s_sq[2][tid] + s_sq[3][tid];
    atomicAdd(&gsum[tid], v);
    atomicAdd(&gsq[tid], q);
  }
}

// ---------------------------------------------------------------------------
// passB: recompute conv0 -> BN0+ReLU -> conv1 stats (no y1 store).
// ---------------------------------------------------------------------------
__global__ __launch_bounds__(256) void passB_kernel(
    const float* __restrict__ xyz, const float* __restrict__ pts,
    const float* __restrict__ pts_t, int use_pt,
    const float* __restrict__ new_xyz, const int* __restrict__ idxo,
    const float* __restrict__ wt0, const float* __restrict__ b0,
    const float* __restrict__ scale0, const float* __restrict__ shift0,
    const float* __restrict__ wt1, const float* __restrict__ b1,
    float* __restrict__ gsum, float* __restrict__ gsq)
{
  __shared__ __align__(16) float bufA[C0_ * 72];
  __shared__ __align__(16) float bufB[128 * 72];
  __shared__ float s_sum[4][128], s_sq[4][128];
  const int tid = threadIdx.x;
  const int lane = tid & 63, wid = tid >> 6;
  const int cog = tid & 15, pg = tid >> 4;
  float bias0[8], bias1[8], sc0[8], sh0[8];
#pragma unroll
  for (int j = 0; j < 8; ++j) {
    bias0[j] = b0[cog * 8 + j];
    bias1[j] = b1[cog * 8 + j];
    sc0[j] = scale0[cog * 8 + j];
    sh0[j] = shift0[cog * 8 + j];
  }
  float ssum[8], ssq[8];
#pragma unroll
  for (int j = 0; j < 8; ++j) { ssum[j] = 0.f; ssq[j] = 0.f; }

  for (int t = 0; t < 4; ++t) {
    const int gp0 = (blockIdx.x * 4 + t) * 64;
    __syncthreads();
    stage_x0(gp0, tid, xyz, pts, pts_t, use_pt, new_xyz, idxo, bufA);
    __syncthreads();
    float acc[4][8];
#pragma unroll
    for (int i = 0; i < 4; ++i)
#pragma unroll
      for (int j = 0; j < 8; ++j) acc[i][j] = 0.f;
    conv8<C0_>(bufA, wt0 + cog * 8, pg, acc);
#pragma unroll
    for (int i = 0; i < 4; ++i)
#pragma unroll
      for (int j = 0; j < 8; ++j) {
        float y = acc[i][j] + bias0[j];
        bufB[(cog * 8 + j) * 72 + pg * 4 + i] = fmaxf(0.f, fmaf(y, sc0[j], sh0[j]));
      }
    __syncthreads();
#pragma unroll
    for (int i = 0; i < 4; ++i)
#pragma unroll
      for (int j = 0; j < 8; ++j) acc[i][j] = 0.f;
    conv8<128>(bufB, wt1 + cog * 8, pg, acc);
#pragma unroll
    for (int i = 0; i < 4; ++i)
#pragma unroll
      for (int j = 0; j < 8; ++j) {
        float y = acc[i][j] + bias1[j];
        ssum[j] += y;
        ssq[j] = fmaf(y, y, ssq[j]);
      }
  }
#pragma unroll
  for (int j = 0; j < 8; ++j) {
    float v = ssum[j];
    v += __shfl_xor(v, 16, 64); v += __shfl_xor(v, 32, 64);
    float q = ssq[j];
    q += __shfl_xor(q, 16, 64); q += __shfl_xor(q, 32, 64);
    if (lane < 16) { s_sum[wid][lane * 8 + j] = v; s_sq[wid][lane * 8 + j] = q; }
  }
  __syncthreads();
  if (tid < 128) {
    float v = s_sum[0][tid] + s_sum[1][tid] + s_sum[2][tid] + s_sum[3][tid];
    float q = s_sq[0][tid] + s_sq[1][tid] + s_sq[2][tid] + s_sq[3][tid];
    atomicAdd(&gsum[tid], v);
    atomicAdd(&gsq[tid], q);
  }
}

// ---------------------------------------------------------------------------
// passC: recompute conv0->BN0->conv1->BN1->conv2; emit per-centroid max/min
// of y2 (BN2+ReLU is monotone affine) + conv2 stats. Never stores y2.
// ---------------------------------------------------------------------------
__global__ __launch_bounds__(256) void passC_kernel(
    const float* __restrict__ xyz, const float* __restrict__ pts,
    const float* __restrict__ pts_t, int use_pt,
    const float* __restrict__ new_xyz, const int* __restrict__ idxo,
    const float* __restrict__ wt0, const float* __restrict__ b0,
    const float* __restrict__ scale0, const float* __restrict__ shift0,
    const float* __restrict__ wt1, const float* __restrict__ b1,
    const float* __restrict__ scale1, const float* __restrict__ shift1,
    const float* __restrict__ wt2, const float* __restrict__ b2,
    float* __restrict__ m2max, float* __restrict__ m2min,
    float* __restrict__ gsum, float* __restrict__ gsq)
{
  __shared__ __align__(16) float bufA[128 * 72];   // x0 (67 rows) then x2 (128 rows)
  __shared__ __align__(16) float bufB[128 * 72];   // x1
  __shared__ float s_m[4 * 256], s_n[4 * 256];
  __shared__ float s_sum[4][256], s_sq[4][256];
  const int tid = threadIdx.x;
  const int lane = tid & 63, wid = tid >> 6;
  const int cog = tid & 15, pg = tid >> 4;
  const int co0 = cog * 16;
  float bias0[8], bias1[8], sc0[8], sh0[8], sc1[8], sh1[8];
#pragma unroll
  for (int j = 0; j < 8; ++j) {
    bias0[j] = b0[cog * 8 + j];
    bias1[j] = b1[cog * 8 + j];
    sc0[j] = scale0[cog * 8 + j];
    sh0[j] = shift0[cog * 8 + j];
    sc1[j] = scale1[cog * 8 + j];
    sh1[j] = shift1[cog * 8 + j];
  }
  float bias2[16];
#pragma unroll
  for (int j = 0; j < 16; ++j) bias2[j] = b2[co0 + j];
  float ssum[16], ssq[16];
#pragma unroll
  for (int j = 0; j < 16; ++j) { ssum[j] = 0.f; ssq[j] = 0.f; }

  for (int t = 0; t < 4; ++t) {
    const int gp0 = (blockIdx.x * 4 + t) * 64;
    __syncthreads();
    stage_x0(gp0, tid, xyz, pts, pts_t, use_pt, new_xyz, idxo, bufA);
    __syncthreads();
    // conv0 -> x1
    {
      float acc[4][8];
#pragma unroll
      for (int i = 0; i < 4; ++i)
#pragma unroll
        for (int j = 0; j < 8; ++j) acc[i][j] = 0.f;
      conv8<C0_>(bufA, wt0 + cog * 8, pg, acc);
#pragma unroll
      for (int i = 0; i < 4; ++i)
#pragma unroll
        for (int j = 0; j < 8; ++j) {
          float y = acc[i][j] + bias0[j];
          bufB[(cog * 8 + j) * 72 + pg * 4 + i] = fmaxf(0.f, fmaf(y, sc0[j], sh0[j]));
        }
    }
    __syncthreads();                 // all conv0 reads of bufA done
    // conv1 -> x2 (into bufA)
    {
      float acc[4][8];
#pragma unroll
      for (int i = 0; i < 4; ++i)
#pragma unroll
        for (int j = 0; j < 8; ++j) acc[i][j] = 0.f;
      conv8<128>(bufB, wt1 + cog * 8, pg, acc);
#pragma unroll
      for (int i = 0; i < 4; ++i)
#pragma unroll
        for (int j = 0; j < 8; ++j) {
          float y = acc[i][j] + bias1[j];
          bufA[(cog * 8 + j) * 72 + pg * 4 + i] = fmaxf(0.f, fmaf(y, sc1[j], sh1[j]));
        }
    }
    __syncthreads();
    // conv2 -> stats + per-centroid max/min
    {
      float acc[4][16];
#pragma unroll
      for (int i = 0; i < 4; ++i)
#pragma unroll
        for (int j = 0; j < 16; ++j) acc[i][j] = 0.f;
      const float* wrow = wt2 + co0;
      for (int ci = 0; ci < 128; ++ci) {
        float4 x4 = *(const float4*)&bufA[ci * 72 + pg * 4];
        float xr[4] = {x4.x, x4.y, x4.z, x4.w};
        float wv[16];
#pragma unroll
        for (int w4 = 0; w4 < 4; ++w4) {
          float4 wf = *(const float4*)&wrow[ci * 256 + w4 * 4];
          wv[w4 * 4 + 0] = wf.x; wv[w4 * 4 + 1] = wf.y;
          wv[w4 * 4 + 2] = wf.z; wv[w4 * 4 + 3] = wf.w;
        }
#pragma unroll
        for (int i = 0; i < 4; ++i)
#pragma unroll
          for (int j = 0; j < 16; ++j) acc[i][j] = fmaf(xr[i], wv[j], acc[i][j]);
      }
      float mx[16], mn[16];
#pragma unroll
      for (int j = 0; j < 16; ++j) { mx[j] = -3.4e38f; mn[j] = 3.4e38f; }
#pragma unroll
      for (int i = 0; i < 4; ++i)
#pragma unroll
        for (int j = 0; j < 16; ++j) {
          float y = acc[i][j] + bias2[j];
          ssum[j] += y;
          ssq[j] = fmaf(y, y, ssq[j]);
          mx[j] = fmaxf(mx[j], y);
          mn[j] = fminf(mn[j], y);
        }
#pragma unroll
      for (int j = 0; j < 16; ++j) {
        float a = mx[j];
        a = fmaxf(a, __shfl_xor(a, 16, 64)); a = fmaxf(a, __shfl_xor(a, 32, 64));
        float c = mn[j];
        c = fminf(c, __shfl_xor(c, 16, 64)); c = fminf(c, __shfl_xor(c, 32, 64));
        if (lane < 16) {
          s_m[wid * 256 + lane * 16 + j] = a;
          s_n[wid * 256 + lane * 16 + j] = c;
        }
      }
      __syncthreads();
      {
        int co = tid;
        size_t bsA = (size_t)(gp0 >> 5);   // global (b*S+s) of first centroid
        m2max[bsA * 256 + co]       = fmaxf(s_m[co], s_m[256 + co]);
        m2max[(bsA + 1) * 256 + co] = fmaxf(s_m[512 + co], s_m[768 + co]);
        m2min[bsA * 256 + co]       = fminf(s_n[co], s_n[256 + co]);
        m2min[(bsA + 1) * 256 + co] = fminf(s_n[512 + co], s_n[768 + co]);
      }
    }
  }
#pragma unroll
  for (int j = 0; j < 16; ++j) {
    float v = ssum[j];
    v += __shfl_xor(v, 16, 64); v += __shfl_xor(v, 32, 64);
    float q = ssq[j];
    q += __shfl_xor(q, 16, 64); q += __shfl_xor(q, 32, 64);
    if (lane < 16) { s_sum[wid][lane * 16 + j] = v; s_sq[wid][lane * 16 + j] = q; }
  }
  __syncthreads();
  {
    int co = tid;
    float v = s_sum[0][co] + s_sum[1][co] + s_sum[2][co] + s_sum[3][co];
    float q = s_sq[0][co] + s_sq[1][co] + s_sq[2][co] + s_sq[3][co];
    atomicAdd(&gsum[co], v);
    atomicAdd(&gsq[co], q);
  }
}

__global__ void stats_kernel(
    const float* __restrict__ gsum, const float* __restrict__ gsq,
    const float* __restrict__ g, const float* __restrict__ be,
    float* __restrict__ scale, float* __restrict__ shift, int C)
{
  int c = threadIdx.x;
  if (c >= C) return;
  const float invP = 1.0f / (float)P_;   // P = 2^18, exact division
  float mean = gsum[c] * invP;
  float var = fmaxf(gsq[c] * invP - mean * mean, 0.f);
  float r = 1.0f / sqrtf(var + 1e-5f);
  float sc = g[c] * r;
  scale[c] = sc;
  shift[c] = be[c] - mean * sc;
}

// feat[b][c][s] = relu(scale2*(scale2>=0 ? max : min) + shift2), transposed.
__global__ __launch_bounds__(256) void final_kernel(
    const float* __restrict__ m2max, const float* __restrict__ m2min,
    const float* __restrict__ scale2, const float* __restrict__ shift2,
    float* __restrict__ d_out)
{
  __shared__ float tmx[64][65], tmn[64][65];
  const int blk = blockIdx.x;
  const int b = blk >> 7;
  const int st = (blk >> 2) & 31;
  const int ct = blk & 3;
  const int s0 = st * 64, c0 = ct * 64;
  const int tx = threadIdx.x & 63, ty = threadIdx.x >> 6;
#pragma unroll
  for (int r = 0; r < 16; ++r) {
    int sl = r * 4 + ty;
    size_t src = ((size_t)(b * S_ + s0 + sl)) * 256 + c0 + tx;
    tmx[sl][tx] = m2max[src];
    tmn[sl][tx] = m2min[src];
  }
  __syncthreads();
#pragma unroll
  for (int r = 0; r < 16; ++r) {
    int cl = r * 4 + ty;
    int c = c0 + cl;
    float sc = scale2[c], sh = shift2[c];
    float m = (sc >= 0.f) ? tmx[tx][cl] : tmn[tx][cl];
    d_out[FEAT_OFF + ((size_t)(b * C3_ + c)) * S_ + s0 + tx] =
        fmaxf(0.f, fmaf(m, sc, sh));
  }
}

// ---------------------------------------------------------------------------
extern "C" void kernel_launch(void* const* d_in, const int* in_sizes, int n_in,
                              void* d_out_v, int out_size, void* d_ws,
                              size_t ws_size, hipStream_t stream)
{
  (void)in_sizes; (void)n_in; (void)out_size;
  const float* xyz = (const float*)d_in[0];
  const float* pts = (const float*)d_in[1];
  const int* seed = (const int*)d_in[2];
  const int* fstart = (const int*)d_in[3];
  const float* W0 = (const float*)d_in[4];
  const float* b0 = (const float*)d_in[5];
  const float* g0 = (const float*)d_in[6];
  const float* be0 = (const float*)d_in[7];
  const float* W1 = (const float*)d_in[8];
  const float* b1 = (const float*)d_in[9];
  const float* g1 = (const float*)d_in[10];
  const float* be1 = (const float*)d_in[11];
  const float* W2 = (const float*)d_in[12];
  const float* b2 = (const float*)d_in[13];
  const float* g2 = (const float*)d_in[14];
  const float* be2 = (const float*)d_in[15];
  float* out = (float*)d_out_v;
  char* ws = (char*)d_ws;

  size_t off = 0;
  auto alloc = [&](size_t bytes) -> void* {
    off = (off + 255) & ~(size_t)255;
    void* p = ws + off;
    off += bytes;
    return p;
  };
  // Compact layout: ~18 MB (+16 MB pts_t only if ws_size allows).
  int*   fps_idx = (int*)alloc((size_t)B_ * S_ * 4);
  float* new_xyz = (float*)alloc((size_t)B_ * S_ * 3 * 4);
  int*   idxo    = (int*)alloc((size_t)B_ * S_ * K_ * 4);
  float* m2max   = (float*)alloc((size_t)B_ * S_ * 256 * 4);
  float* m2min   = (float*)alloc((size_t)B_ * S_ * 256 * 4);
  float* stats   = (float*)alloc(1024 * 4);
  float* scsh    = (float*)alloc(1024 * 4);
  float* wt0     = (float*)alloc((size_t)67 * 128 * 4);
  float* wt1     = (float*)alloc((size_t)128 * 128 * 4);
  float* wt2     = (float*)alloc((size_t)128 * 256 * 4);
  unsigned long long* comm =
      (unsigned long long*)alloc((size_t)B_ * 2 * 32 * 8);   // 2 KB hot slots
  const int use_pt = (ws_size >= (off + (size_t)B_ * N_ * D_ * 4 + (1u << 20))) ? 1 : 0;
  float* pts_t   = use_pt ? (float*)alloc((size_t)B_ * N_ * D_ * 4) : (float*)ws;

  float* gsum0 = stats, *gsq0 = stats + 128;
  float* gsum1 = stats + 256, *gsq1 = stats + 384;
  float* gsum2 = stats + 512, *gsq2 = stats + 768;
  float* scale0 = scsh, *shift0 = scsh + 128;
  float* scale1 = scsh + 256, *shift1 = scsh + 384;
  float* scale2 = scsh + 512, *shift2 = scsh + 768;

  hipMemsetAsync(stats, 0, 1024 * 4, stream);
  hipMemsetAsync(comm, 0, (size_t)B_ * 2 * 32 * 8, stream);
  transpose_w_kernel<<<226, 256, 0, stream>>>(W0, W1, W2, wt0, wt1, wt2);
  if (use_pt)
    transpose_pts_kernel<<<B_ * 256, 256, 0, stream>>>(pts, pts_t);
  fps_kernel<<<B_ * 2, 1024, 0, stream>>>(xyz, fstart, comm, fps_idx, new_xyz, out);
  seed_gather_kernel<<<(B_ * S_ + 255) / 256, 256, 0, stream>>>(seed, fps_idx, out);
  ballquery_kernel<<<B_ * S_ / 4, 256, 0, stream>>>(xyz, new_xyz, idxo);
  passA_kernel<<<1024, 256, 0, stream>>>(xyz, pts, pts_t, use_pt, new_xyz, idxo,
                                         wt0, b0, gsum0, gsq0);
  stats_kernel<<<1, 128, 0, stream>>>(gsum0, gsq0, g0, be0, scale0, shift0, 128);
  passB_kernel<<<1024, 256, 0, stream>>>(xyz, pts, pts_t, use_pt, new_xyz, idxo,
                                         wt0, b0, scale0, shift0, wt1, b1,
                                         gsum1, gsq1);
  stats_kernel<<<1, 128, 0, stream>>>(gsum1, gsq1, g1, be1, scale1, shift1, 128);
  passC_kernel<<<1024, 256, 0, stream>>>(xyz, pts, pts_t, use_pt, new_xyz, idxo,
                                         wt0, b0, scale0, shift0, wt1, b1,
                                         scale1, shift1, wt2, b2,
                                         m2max, m2min, gsum2, gsq2);
  stats_kernel<<<1, 256, 0, stream>>>(gsum2, gsq2, g2, be2, scale2, shift2, 256);
  final_kernel<<<512, 256, 0, stream>>>(m2max, m2min, scale2, shift2, out);
}

// Round 8
// 4191.372 us; speedup vs baseline: 1.3717x; 1.3717x over previous
//
#include <hip/hip_runtime.h>
#include <cstdint>
#include <cstddef>

#define B_ 4
#define N_ 16384
#define S_ 2048
#define K_ 32
#define D_ 64
#define C0_ 67
#define C3_ 256
#define P_ (B_*S_*K_)           // 262144 pixels
#define FEAT_OFF 24576          // B*3*S
#define SEED_OFF (24576 + B_*C3_*S_)

// ---------------------------------------------------------------------------
// FPS: R12. Back to the PROVEN best config (R1: one block/batch, 512 thr,
// 32 pts/thread — 3512us fps, best total 4903us). Multi-block variants
// (R10 16-way, R11 pairwise) lose to cross-block atomic latency; storage
// experiments (scratch/LDS/waves_per_eu) were all flat -> the loop is
// issue+latency bound, and ~1/3 of the iteration is the OLD reduce's ~21
// dependent shuffles (xor16/32 lower to ds_bpermute, ~50-60cyc each,
// value AND index both ride the tree).
// R12 changes (selection provably identical to reference):
//  - scan tracks max VALUE only: mx = max3(m0,m1,mx) (v_max3_f32); no
//    per-point argmax cmp/cndmask (-2.5 ops/pt).
//  - reduce: 6-stage value-only wave reduce, partials in LDS, every
//    thread folds 8 partials -> bmax (fmax is exactly associative).
//  - index recovery LAZY: only waves with mx==bmax (execz-skip others)
//    rescan their 32 dmin for == bmax (descending overwrite -> smallest
//    own index) and LDS-atomicMin the global index. Min global index
//    over ties == reference first-index argmax -> bit-identical.
//  - s_cand uses a 4-slot rotation: slot it&3 is read in [B2(it),B1(it+1)];
//    its next reset (at it+2, pre-B1) is separated by 2 barriers -> no race.
// Distance chain unchanged (bit-matched): d = fma(dz,dz, fma(dy,dy, dx*dx)).
// ---------------------------------------------------------------------------
__global__ __launch_bounds__(512, 2) void fps_kernel(
    const float* __restrict__ xyz,
    const int* __restrict__ fps_start,
    int* __restrict__ fps_idx, float* __restrict__ new_xyz,
    float* __restrict__ d_out)
{
  const int b = blockIdx.x;
  const int tid = threadIdx.x;
  const int lane = tid & 63;
  const int wid = tid >> 6;          // 0..7
  const float* __restrict__ xb = xyz + (size_t)b * 3 * N_;
  constexpr int PTS = N_ / 512;      // 32
  float px[PTS], py[PTS], pz[PTS], dmin[PTS];
#pragma unroll
  for (int i = 0; i < PTS; ++i) {
    int j = i * 512 + tid;
    px[i] = xb[j]; py[i] = xb[N_ + j]; pz[i] = xb[2 * N_ + j];
    dmin[i] = 1e10f;
  }
  __shared__ float s_val[2][8];
  __shared__ int   s_cand[4];
  if (tid == 0) {
    s_cand[0] = 0x7fffffff; s_cand[1] = 0x7fffffff;
    s_cand[2] = 0x7fffffff; s_cand[3] = 0x7fffffff;
  }
  int cur = fps_start[b];
  __syncthreads();

  for (int it = 0; it < S_; ++it) {
    const int buf = it & 1;
    const int cslot = it & 3;
    int cs = __builtin_amdgcn_readfirstlane(cur);
    float cx = xb[cs], cy = xb[N_ + cs], cz = xb[2 * N_ + cs];
    if (tid == 0) {
      fps_idx[b * S_ + it] = cs;
      new_xyz[(b * S_ + it) * 3 + 0] = cx;
      new_xyz[(b * S_ + it) * 3 + 1] = cy;
      new_xyz[(b * S_ + it) * 3 + 2] = cz;
      d_out[(b * 3 + 0) * S_ + it] = cx;
      d_out[(b * 3 + 1) * S_ + it] = cy;
      d_out[(b * 3 + 2) * S_ + it] = cz;
      s_cand[(it + 2) & 3] = 0x7fffffff;   // reset slot for iter it+2 (2-barrier-safe)
    }
    // scan: update dmin, track max VALUE only (pairs -> v_max3_f32)
    float mx = -1e30f;
#pragma unroll
    for (int i = 0; i < PTS; i += 2) {
      float dx0 = __fadd_rn(px[i], -cx);
      float dy0 = __fadd_rn(py[i], -cy);
      float dz0 = __fadd_rn(pz[i], -cz);
      float d0 = fmaf(dz0, dz0, fmaf(dy0, dy0, __fmul_rn(dx0, dx0)));
      float m0 = fminf(dmin[i], d0); dmin[i] = m0;
      float dx1 = __fadd_rn(px[i + 1], -cx);
      float dy1 = __fadd_rn(py[i + 1], -cy);
      float dz1 = __fadd_rn(pz[i + 1], -cz);
      float d1 = fmaf(dz1, dz1, fmaf(dy1, dy1, __fmul_rn(dx1, dx1)));
      float m1 = fminf(dmin[i + 1], d1); dmin[i + 1] = m1;
      mx = fmaxf(fmaxf(m0, m1), mx);       // max3
    }
    // value-only wave reduce (6 stages)
    float wv = mx;
#pragma unroll
    for (int off = 1; off < 64; off <<= 1)
      wv = fmaxf(wv, __shfl_xor(wv, off, 64));
    if (lane == 0) s_val[buf][wid] = wv;
    __syncthreads();                       // B1
    // block max: every thread folds the 8 wave partials (broadcast reads)
    float bmax = fmaxf(fmaxf(fmaxf(s_val[buf][0], s_val[buf][1]),
                             fmaxf(s_val[buf][2], s_val[buf][3])),
                       fmaxf(fmaxf(s_val[buf][4], s_val[buf][5]),
                             fmaxf(s_val[buf][6], s_val[buf][7])));
    // lazy index recovery: only waves holding the max pay the rescan
    if (mx == bmax) {
      int cand = 0x7fffffff;
#pragma unroll
      for (int i = PTS - 1; i >= 0; --i)   // descending: keeps smallest i
        cand = (dmin[i] == bmax) ? (i * 512 + tid) : cand;
      atomicMin(&s_cand[cslot], cand);
    }
    __syncthreads();                       // B2
    cur = s_cand[cslot];
  }
}

// seed_out[b][s] = (float)seed_inds[b][fps_idx[b][s]]
__global__ __launch_bounds__(256) void seed_gather_kernel(
    const int* __restrict__ seed_inds, const int* __restrict__ fps_idx,
    float* __restrict__ d_out)
{
  int i = blockIdx.x * 256 + threadIdx.x;      // 0 .. B*S-1
  if (i < B_ * S_) {
    int b = i >> 11;                           // i / S_
    d_out[SEED_OFF + i] = (float)seed_inds[(size_t)b * N_ + fps_idx[i]];
  }
}

// ---------------------------------------------------------------------------
// Ball query: one wave per centroid; first K in-ball indices ascending,
// pad with first hit.
// ---------------------------------------------------------------------------
__global__ __launch_bounds__(256) void ballquery_kernel(
    const float* __restrict__ xyz, const float* __restrict__ new_xyz,
    int* __restrict__ idxo)
{
  const int c = blockIdx.x * 4 + (threadIdx.x >> 6);
  const int lane = threadIdx.x & 63;
  const int b = c >> 11;
  const float* __restrict__ xb = xyz + (size_t)b * 3 * N_;
  float cx = new_xyz[c * 3 + 0], cy = new_xyz[c * 3 + 1], cz = new_xyz[c * 3 + 2];
  float css = __fadd_rn(__fadd_rn(__fmul_rn(cx, cx), __fmul_rn(cy, cy)),
                        __fmul_rn(cz, cz));
  const double rr = 0.3 * 0.3;
  int cnt = 0, first = -1;
  for (int base = 0; base < N_; base += 64) {
    int j = base + lane;
    float x = xb[j], y = xb[N_ + j], z = xb[2 * N_ + j];
    float pss = __fadd_rn(__fadd_rn(__fmul_rn(x, x), __fmul_rn(y, y)),
                          __fmul_rn(z, z));
    float dot = __fadd_rn(__fadd_rn(__fmul_rn(cx, x), __fmul_rn(cy, y)),
                          __fmul_rn(cz, z));
    float d = __fadd_rn(__fadd_rn(__fmul_rn(-2.f, dot), css), pss);
    bool in = (double)d <= rr;
    unsigned long long m = __ballot(in);
    if (m) {
      if (first < 0) first = base + (__ffsll((long long)m) - 1);
      int rank = (int)__popcll(m & ((1ull << lane) - 1ull));
      int pos = cnt + rank;
      if (in && pos < K_) idxo[(size_t)c * K_ + pos] = j;
      cnt += (int)__popcll(m);
      if (cnt >= K_) break;
    }
  }
  for (int p = cnt + lane; p < K_; p += 64) idxo[(size_t)c * K_ + p] = first;
}

// ---------------------------------------------------------------------------
// points (B,D,N) -> (B,N,D) (only used when ws_size permits).
// ---------------------------------------------------------------------------
__global__ __launch_bounds__(256) void transpose_pts_kernel(
    const float* __restrict__ pts, float* __restrict__ pts_t)
{
  __shared__ float tile[64][65];
  const int blk = blockIdx.x;
  const int b = blk >> 8;
  const int n0 = (blk & 255) * 64;
  const int tx = threadIdx.x & 63, ty = threadIdx.x >> 6;
#pragma unroll
  for (int r = 0; r < 16; ++r) {
    int d = r * 4 + ty;
    tile[d][tx] = pts[((size_t)b * D_ + d) * N_ + n0 + tx];
  }
  __syncthreads();
#pragma unroll
  for (int r = 0; r < 16; ++r) {
    int nl = r * 4 + ty;
    pts_t[((size_t)b * N_ + n0 + nl) * D_ + tx] = tile[tx][nl];
  }
}

__global__ void transpose_w_kernel(
    const float* __restrict__ W0, const float* __restrict__ W1,
    const float* __restrict__ W2, float* __restrict__ wt0,
    float* __restrict__ wt1, float* __restrict__ wt2)
{
  int i = blockIdx.x * 256 + threadIdx.x;
  if (i < 128 * 67) { int co = i / 67, ci = i % 67; wt0[ci * 128 + co] = W0[i]; }
  int i1 = i - 128 * 67;
  if (i1 >= 0 && i1 < 128 * 128) { int co = i1 >> 7, ci = i1 & 127; wt1[ci * 128 + co] = W1[i1]; }
  int i2 = i1 - 128 * 128;
  if (i2 >= 0 && i2 < 256 * 128) { int co = i2 >> 7, ci = i2 & 127; wt2[ci * 256 + co] = W2[i2]; }
}

// ---------------------------------------------------------------------------
// Shared device helpers for the recompute passes.
// ---------------------------------------------------------------------------
__device__ __forceinline__ void stage_x0(
    int gp0, int tid, const float* __restrict__ xyz,
    const float* __restrict__ pts, const float* __restrict__ pts_t, int use_pt,
    const float* __restrict__ new_xyz, const int* __restrict__ idxo,
    float* __restrict__ bufA)
{
  int pxl = tid >> 2, q = tid & 3;
  int gp = gp0 + pxl;
  int b = gp >> 16;
  int s = (gp >> 5) & (S_ - 1);
  int j = idxo[gp];
  if (use_pt) {
    const float* src = pts_t + ((size_t)b * N_ + j) * 64 + q * 16;
#pragma unroll
    for (int v = 0; v < 4; ++v) {
      float4 f = *(const float4*)(src + v * 4);
      int c = 3 + q * 16 + v * 4;
      bufA[(c + 0) * 72 + pxl] = f.x;
      bufA[(c + 1) * 72 + pxl] = f.y;
      bufA[(c + 2) * 72 + pxl] = f.z;
      bufA[(c + 3) * 72 + pxl] = f.w;
    }
  } else {
    const float* src = pts + ((size_t)b * D_ + q * 16) * N_ + j;
#pragma unroll
    for (int v = 0; v < 16; ++v)
      bufA[(3 + q * 16 + v) * 72 + pxl] = src[(size_t)v * N_];
  }
  if (q == 0) {
    const float* xb = xyz + (size_t)b * 3 * N_;
    int c3 = (b * S_ + s) * 3;
    bufA[0 * 72 + pxl] = xb[j] - new_xyz[c3 + 0];
    bufA[1 * 72 + pxl] = xb[N_ + j] - new_xyz[c3 + 1];
    bufA[2 * 72 + pxl] = xb[2 * N_ + j] - new_xyz[c3 + 2];
  }
}

// 8-cout conv micro-tile: acc[4 px][8 co] += buf[ci][pg*4..] * w[ci][cog*8..]
template<int CIN>
__device__ __forceinline__ void conv8(
    const float* __restrict__ buf, const float* __restrict__ wrow, int pg,
    float acc[4][8])
{
  for (int ci = 0; ci < CIN; ++ci) {
    float4 x4 = *(const float4*)&buf[ci * 72 + pg * 4];
    float4 wa = *(const float4*)&wrow[ci * 128];
    float4 wb = *(const float4*)&wrow[ci * 128 + 4];
    float xr[4] = {x4.x, x4.y, x4.z, x4.w};
    float wv[8] = {wa.x, wa.y, wa.z, wa.w, wb.x, wb.y, wb.z, wb.w};
#pragma unroll
    for (int i = 0; i < 4; ++i)
#pragma unroll
      for (int j = 0; j < 8; ++j) acc[i][j] = fmaf(xr[i], wv[j], acc[i][j]);
  }
}

// ---------------------------------------------------------------------------
// passA: conv0 stats only (no y0 store).
// ---------------------------------------------------------------------------
__global__ __launch_bounds__(256) void passA_kernel(
    const float* __restrict__ xyz, const float* __restrict__ pts,
    const float* __restrict__ pts_t, int use_pt,
    const float* __restrict__ new_xyz, const int* __restrict__ idxo,
    const float* __restrict__ wt0, const float* __restrict__ b0,
    float* __restrict__ gsum, float* __restrict__ gsq)
{
  __shared__ __align__(16) float bufA[C0_ * 72];
  __shared__ float s_sum[4][128], s_sq[4][128];
  const int tid = threadIdx.x;
  const int lane = tid & 63, wid = tid >> 6;
  const int cog = tid & 15, pg = tid >> 4;
  float bias[8];
#pragma unroll
  for (int j = 0; j < 8; ++j) bias[j] = b0[cog * 8 + j];
  float ssum[8], ssq[8];
#pragma unroll
  for (int j = 0; j < 8; ++j) { ssum[j] = 0.f; ssq[j] = 0.f; }

  for (int t = 0; t < 4; ++t) {
    const int gp0 = (blockIdx.x * 4 + t) * 64;
    __syncthreads();
    stage_x0(gp0, tid, xyz, pts, pts_t, use_pt, new_xyz, idxo, bufA);
    __syncthreads();
    float acc[4][8];
#pragma unroll
    for (int i = 0; i < 4; ++i)
#pragma unroll
      for (int j = 0; j < 8; ++j) acc[i][j] = 0.f;
    conv8<C0_>(bufA, wt0 + cog * 8, pg, acc);
#pragma unroll
    for (int i = 0; i < 4; ++i)
#pragma unroll
      for (int j = 0; j < 8; ++j) {
        float y = acc[i][j] + bias[j];
        ssum[j] += y;
        ssq[j] = fmaf(y, y, ssq[j]);
      }
  }
#pragma unroll
  for (int j = 0; j < 8; ++j) {
    float v = ssum[j];
    v += __shfl_xor(v, 16, 64); v += __shfl_xor(v, 32, 64);
    float q = ssq[j];
    q += __shfl_xor(q, 16, 64); q += __shfl_xor(q, 32, 64);
    if (lane < 16) { s_sum[wid][lane * 8 + j] = v; s_sq[wid][lane * 8 + j] = q; }
  }
  __syncthreads();
  if (tid < 128) {
    float v = s_sum[0][tid] + s_sum[1][tid] + s_sum[2][tid] + s_sum[3][tid];
    float q = s_sq[0][tid] + s_sq[1][tid] + s_sq[2][tid] + s_sq[3][tid];
    atomicAdd(&gsum[tid], v);
    atomicAdd(&gsq[tid], q);
  }
}

// ---------------------------------------------------------------------------
// passB: recompute conv0 -> BN0+ReLU -> conv1 stats (no y1 store).
// ---------------------------------------------------------------------------
__global__ __launch_bounds__(256) void passB_kernel(
    const float* __restrict__ xyz, const float* __restrict__ pts,
    const float* __restrict__ pts_t, int use_pt,
    const float* __restrict__ new_xyz, const int* __restrict__ idxo,
    const float* __restrict__ wt0, const float* __restrict__ b0,
    const float* __restrict__ scale0, const float* __restrict__ shift0,
    const float* __restrict__ wt1, const float* __restrict__ b1,
    float* __restrict__ gsum, float* __restrict__ gsq)
{
  __shared__ __align__(16) float bufA[C0_ * 72];
  __shared__ __align__(16) float bufB[128 * 72];
  __shared__ float s_sum[4][128], s_sq[4][128];
  const int tid = threadIdx.x;
  const int lane = tid & 63, wid = tid >> 6;
  const int cog = tid & 15, pg = tid >> 4;
  float bias0[8], bias1[8], sc0[8], sh0[8];
#pragma unroll
  for (int j = 0; j < 8; ++j) {
    bias0[j] = b0[cog * 8 + j];
    bias1[j] = b1[cog * 8 + j];
    sc0[j] = scale0[cog * 8 + j];
    sh0[j] = shift0[cog * 8 + j];
  }
  float ssum[8], ssq[8];
#pragma unroll
  for (int j = 0; j < 8; ++j) { ssum[j] = 0.f; ssq[j] = 0.f; }

  for (int t = 0; t < 4; ++t) {
    const int gp0 = (blockIdx.x * 4 + t) * 64;
    __syncthreads();
    stage_x0(gp0, tid, xyz, pts, pts_t, use_pt, new_xyz, idxo, bufA);
    __syncthreads();
    float acc[4][8];
#pragma unroll
    for (int i = 0; i < 4; ++i)
#pragma unroll
      for (int j = 0; j < 8; ++j) acc[i][j] = 0.f;
    conv8<C0_>(bufA, wt0 + cog * 8, pg, acc);
#pragma unroll
    for (int i = 0; i < 4; ++i)
#pragma unroll
      for (int j = 0; j < 8; ++j) {
        float y = acc[i][j] + bias0[j];
        bufB[(cog * 8 + j) * 72 + pg * 4 + i] = fmaxf(0.f, fmaf(y, sc0[j], sh0[j]));
      }
    __syncthreads();
#pragma unroll
    for (int i = 0; i < 4; ++i)
#pragma unroll
      for (int j = 0; j < 8; ++j) acc[i][j] = 0.f;
    conv8<128>(bufB, wt1 + cog * 8, pg, acc);
#pragma unroll
    for (int i = 0; i < 4; ++i)
#pragma unroll
      for (int j = 0; j < 8; ++j) {
        float y = acc[i][j] + bias1[j];
        ssum[j] += y;
        ssq[j] = fmaf(y, y, ssq[j]);
      }
  }
#pragma unroll
  for (int j = 0; j < 8; ++j) {
    float v = ssum[j];
    v += __shfl_xor(v, 16, 64); v += __shfl_xor(v, 32, 64);
    float q = ssq[j];
    q += __shfl_xor(q, 16, 64); q += __shfl_xor(q, 32, 64);
    if (lane < 16) { s_sum[wid][lane * 8 + j] = v; s_sq[wid][lane * 8 + j] = q; }
  }
  __syncthreads();
  if (tid < 128) {
    float v = s_sum[0][tid] + s_sum[1][tid] + s_sum[2][tid] + s_sum[3][tid];
    float q = s_sq[0][tid] + s_sq[1][tid] + s_sq[2][tid] + s_sq[3][tid];
    atomicAdd(&gsum[tid], v);
    atomicAdd(&gsq[tid], q);
  }
}

// ---------------------------------------------------------------------------
// passC: recompute conv0->BN0->conv1->BN1->conv2; emit per-centroid max/min
// of y2 (BN2+ReLU is monotone affine) + conv2 stats. Never stores y2.
// ---------------------------------------------------------------------------
__global__ __launch_bounds__(256) void passC_kernel(
    const float* __restrict__ xyz, const float* __restrict__ pts,
    const float* __restrict__ pts_t, int use_pt,
    const float* __restrict__ new_xyz, const int* __restrict__ idxo,
    const float* __restrict__ wt0, const float* __restrict__ b0,
    const float* __restrict__ scale0, const float* __restrict__ shift0,
    const float* __restrict__ wt1, const float* __restrict__ b1,
    const float* __restrict__ scale1, const float* __restrict__ shift1,
    const float* __restrict__ wt2, const float* __restrict__ b2,
    float* __restrict__ m2max, float* __restrict__ m2min,
    float* __restrict__ gsum, float* __restrict__ gsq)
{
  __shared__ __align__(16) float bufA[128 * 72];   // x0 (67 rows) then x2 (128 rows)
  __shared__ __align__(16) float bufB[128 * 72];   // x1
  __shared__ float s_m[4 * 256], s_n[4 * 256];
  __shared__ float s_sum[4][256], s_sq[4][256];
  const int tid = threadIdx.x;
  const int lane = tid & 63, wid = tid >> 6;
  const int cog = tid & 15, pg = tid >> 4;
  const int co0 = cog * 16;
  float bias0[8], bias1[8], sc0[8], sh0[8], sc1[8], sh1[8];
#pragma unroll
  for (int j = 0; j < 8; ++j) {
    bias0[j] = b0[cog * 8 + j];
    bias1[j] = b1[cog * 8 + j];
    sc0[j] = scale0[cog * 8 + j];
    sh0[j] = shift0[cog * 8 + j];
    sc1[j] = scale1[cog * 8 + j];
    sh1[j] = shift1[cog * 8 + j];
  }
  float bias2[16];
#pragma unroll
  for (int j = 0; j < 16; ++j) bias2[j] = b2[co0 + j];
  float ssum[16], ssq[16];
#pragma unroll
  for (int j = 0; j < 16; ++j) { ssum[j] = 0.f; ssq[j] = 0.f; }

  for (int t = 0; t < 4; ++t) {
    const int gp0 = (blockIdx.x * 4 + t) * 64;
    __syncthreads();
    stage_x0(gp0, tid, xyz, pts, pts_t, use_pt, new_xyz, idxo, bufA);
    __syncthreads();
    // conv0 -> x1
    {
      float acc[4][8];
#pragma unroll
      for (int i = 0; i < 4; ++i)
#pragma unroll
        for (int j = 0; j < 8; ++j) acc[i][j] = 0.f;
      conv8<C0_>(bufA, wt0 + cog * 8, pg, acc);
#pragma unroll
      for (int i = 0; i < 4; ++i)
#pragma unroll
        for (int j = 0; j < 8; ++j) {
          float y = acc[i][j] + bias0[j];
          bufB[(cog * 8 + j) * 72 + pg * 4 + i] = fmaxf(0.f, fmaf(y, sc0[j], sh0[j]));
        }
    }
    __syncthreads();                 // all conv0 reads of bufA done
    // conv1 -> x2 (into bufA)
    {
      float acc[4][8];
#pragma unroll
      for (int i = 0; i < 4; ++i)
#pragma unroll
        for (int j = 0; j < 8; ++j) acc[i][j] = 0.f;
      conv8<128>(bufB, wt1 + cog * 8, pg, acc);
#pragma unroll
      for (int i = 0; i < 4; ++i)
#pragma unroll
        for (int j = 0; j < 8; ++j) {
          float y = acc[i][j] + bias1[j];
          bufA[(cog * 8 + j) * 72 + pg * 4 + i] = fmaxf(0.f, fmaf(y, sc1[j], sh1[j]));
        }
    }
    __syncthreads();
    // conv2 -> stats + per-centroid max/min
    {
      float acc[4][16];
#pragma unroll
      for (int i = 0; i < 4; ++i)
#pragma unroll
        for (int j = 0; j < 16; ++j) acc[i][j] = 0.f;
      const float* wrow = wt2 + co0;
      for (int ci = 0; ci < 128; ++ci) {
        float4 x4 = *(const float4*)&bufA[ci * 72 + pg * 4];
        float xr[4] = {x4.x, x4.y, x4.z, x4.w};
        float wv[16];
#pragma unroll
        for (int w4 = 0; w4 < 4; ++w4) {
          float4 wf = *(const float4*)&wrow[ci * 256 + w4 * 4];
          wv[w4 * 4 + 0] = wf.x; wv[w4 * 4 + 1] = wf.y;
          wv[w4 * 4 + 2] = wf.z; wv[w4 * 4 + 3] = wf.w;
        }
#pragma unroll
        for (int i = 0; i < 4; ++i)
#pragma unroll
          for (int j = 0; j < 16; ++j) acc[i][j] = fmaf(xr[i], wv[j], acc[i][j]);
      }
      float mx[16], mn[16];
#pragma unroll
      for (int j = 0; j < 16; ++j) { mx[j] = -3.4e38f; mn[j] = 3.4e38f; }
#pragma unroll
      for (int i = 0; i < 4; ++i)
#pragma unroll
        for (int j = 0; j < 16; ++j) {
          float y = acc[i][j] + bias2[j];
          ssum[j] += y;
          ssq[j] = fmaf(y, y, ssq[j]);
          mx[j] = fmaxf(mx[j], y);
          mn[j] = fminf(mn[j], y);
        }
#pragma unroll
      for (int j = 0; j < 16; ++j) {
        float a = mx[j];
        a = fmaxf(a, __shfl_xor(a, 16, 64)); a = fmaxf(a, __shfl_xor(a, 32, 64));
        float c = mn[j];
        c = fminf(c, __shfl_xor(c, 16, 64)); c = fminf(c, __shfl_xor(c, 32, 64));
        if (lane < 16) {
          s_m[wid * 256 + lane * 16 + j] = a;
          s_n[wid * 256 + lane * 16 + j] = c;
        }
      }
      __syncthreads();
      {
        int co = tid;
        size_t bsA = (size_t)(gp0 >> 5);   // global (b*S+s) of first centroid
        m2max[bsA * 256 + co]       = fmaxf(s_m[co], s_m[256 + co]);
        m2max[(bsA + 1) * 256 + co] = fmaxf(s_m[512 + co], s_m[768 + co]);
        m2min[bsA * 256 + co]       = fminf(s_n[co], s_n[256 + co]);
        m2min[(bsA + 1) * 256 + co] = fminf(s_n[512 + co], s_n[768 + co]);
      }
    }
  }
#pragma unroll
  for (int j = 0; j < 16; ++j) {
    float v = ssum[j];
    v += __shfl_xor(v, 16, 64); v += __shfl_xor(v, 32, 64);
    float q = ssq[j];
    q += __shfl_xor(q, 16, 64); q += __shfl_xor(q, 32, 64);
    if (lane < 16) { s_sum[wid][lane * 16 + j] = v; s_sq[wid][lane * 16 + j] = q; }
  }
  __syncthreads();
  {
    int co = tid;
    float v = s_sum[0][co] + s_sum[1][co] + s_sum[2][co] + s_sum[3][co];
    float q = s_sq[0][co] + s_sq[1][co] + s_sq[2][co] + s_sq[3][co];
    atomicAdd(&gsum[co], v);
    atomicAdd(&gsq[co], q);
  }
}

__global__ void stats_kernel(
    const float* __restrict__ gsum, const float* __restrict__ gsq,
    const float* __restrict__ g, const float* __restrict__ be,
    float* __restrict__ scale, float* __restrict__ shift, int C)
{
  int c = threadIdx.x;
  if (c >= C) return;
  const float invP = 1.0f / (float)P_;   // P = 2^18, exact division
  float mean = gsum[c] * invP;
  float var = fmaxf(gsq[c] * invP - mean * mean, 0.f);
  float r = 1.0f / sqrtf(var + 1e-5f);
  float sc = g[c] * r;
  scale[c] = sc;
  shift[c] = be[c] - mean * sc;
}

// feat[b][c][s] = relu(scale2*(scale2>=0 ? max : min) + shift2), transposed.
__global__ __launch_bounds__(256) void final_kernel(
    const float* __restrict__ m2max, const float* __restrict__ m2min,
    const float* __restrict__ scale2, const float* __restrict__ shift2,
    float* __restrict__ d_out)
{
  __shared__ float tmx[64][65], tmn[64][65];
  const int blk = blockIdx.x;
  const int b = blk >> 7;
  const int st = (blk >> 2) & 31;
  const int ct = blk & 3;
  const int s0 = st * 64, c0 = ct * 64;
  const int tx = threadIdx.x & 63, ty = threadIdx.x >> 6;
#pragma unroll
  for (int r = 0; r < 16; ++r) {
    int sl = r * 4 + ty;
    size_t src = ((size_t)(b * S_ + s0 + sl)) * 256 + c0 + tx;
    tmx[sl][tx] = m2max[src];
    tmn[sl][tx] = m2min[src];
  }
  __syncthreads();
#pragma unroll
  for (int r = 0; r < 16; ++r) {
    int cl = r * 4 + ty;
    int c = c0 + cl;
    float sc = scale2[c], sh = shift2[c];
    float m = (sc >= 0.f) ? tmx[tx][cl] : tmn[tx][cl];
    d_out[FEAT_OFF + ((size_t)(b * C3_ + c)) * S_ + s0 + tx] =
        fmaxf(0.f, fmaf(m, sc, sh));
  }
}

// ---------------------------------------------------------------------------
extern "C" void kernel_launch(void* const* d_in, const int* in_sizes, int n_in,
                              void* d_out_v, int out_size, void* d_ws,
                              size_t ws_size, hipStream_t stream)
{
  (void)in_sizes; (void)n_in; (void)out_size;
  const float* xyz = (const float*)d_in[0];
  const float* pts = (const float*)d_in[1];
  const int* seed = (const int*)d_in[2];
  const int* fstart = (const int*)d_in[3];
  const float* W0 = (const float*)d_in[4];
  const float* b0 = (const float*)d_in[5];
  const float* g0 = (const float*)d_in[6];
  const float* be0 = (const float*)d_in[7];
  const float* W1 = (const float*)d_in[8];
  const float* b1 = (const float*)d_in[9];
  const float* g1 = (const float*)d_in[10];
  const float* be1 = (const float*)d_in[11];
  const float* W2 = (const float*)d_in[12];
  const float* b2 = (const float*)d_in[13];
  const float* g2 = (const float*)d_in[14];
  const float* be2 = (const float*)d_in[15];
  float* out = (float*)d_out_v;
  char* ws = (char*)d_ws;

  size_t off = 0;
  auto alloc = [&](size_t bytes) -> void* {
    off = (off + 255) & ~(size_t)255;
    void* p = ws + off;
    off += bytes;
    return p;
  };
  // Compact layout: ~18 MB (+16 MB pts_t only if ws_size allows).
  int*   fps_idx = (int*)alloc((size_t)B_ * S_ * 4);
  float* new_xyz = (float*)alloc((size_t)B_ * S_ * 3 * 4);
  int*   idxo    = (int*)alloc((size_t)B_ * S_ * K_ * 4);
  float* m2max   = (float*)alloc((size_t)B_ * S_ * 256 * 4);
  float* m2min   = (float*)alloc((size_t)B_ * S_ * 256 * 4);
  float* stats   = (float*)alloc(1024 * 4);
  float* scsh    = (float*)alloc(1024 * 4);
  float* wt0     = (float*)alloc((size_t)67 * 128 * 4);
  float* wt1     = (float*)alloc((size_t)128 * 128 * 4);
  float* wt2     = (float*)alloc((size_t)128 * 256 * 4);
  const int use_pt = (ws_size >= (off + (size_t)B_ * N_ * D_ * 4 + (1u << 20))) ? 1 : 0;
  float* pts_t   = use_pt ? (float*)alloc((size_t)B_ * N_ * D_ * 4) : (float*)ws;

  float* gsum0 = stats, *gsq0 = stats + 128;
  float* gsum1 = stats + 256, *gsq1 = stats + 384;
  float* gsum2 = stats + 512, *gsq2 = stats + 768;
  float* scale0 = scsh, *shift0 = scsh + 128;
  float* scale1 = scsh + 256, *shift1 = scsh + 384;
  float* scale2 = scsh + 512, *shift2 = scsh + 768;

  hipMemsetAsync(stats, 0, 1024 * 4, stream);
  transpose_w_kernel<<<226, 256, 0, stream>>>(W0, W1, W2, wt0, wt1, wt2);
  if (use_pt)
    transpose_pts_kernel<<<B_ * 256, 256, 0, stream>>>(pts, pts_t);
  fps_kernel<<<B_, 512, 0, stream>>>(xyz, fstart, fps_idx, new_xyz, out);
  seed_gather_kernel<<<(B_ * S_ + 255) / 256, 256, 0, stream>>>(seed, fps_idx, out);
  ballquery_kernel<<<B_ * S_ / 4, 256, 0, stream>>>(xyz, new_xyz, idxo);
  passA_kernel<<<1024, 256, 0, stream>>>(xyz, pts, pts_t, use_pt, new_xyz, idxo,
                                         wt0, b0, gsum0, gsq0);
  stats_kernel<<<1, 128, 0, stream>>>(gsum0, gsq0, g0, be0, scale0, shift0, 128);
  passB_kernel<<<1024, 256, 0, stream>>>(xyz, pts, pts_t, use_pt, new_xyz, idxo,
                                         wt0, b0, scale0, shift0, wt1, b1,
                                         gsum1, gsq1);
  stats_kernel<<<1, 128, 0, stream>>>(gsum1, gsq1, g1, be1, scale1, shift1, 128);
  passC_kernel<<<1024, 256, 0, stream>>>(xyz, pts, pts_t, use_pt, new_xyz, idxo,
                                         wt0, b0, scale0, shift0, wt1, b1,
                                         scale1, shift1, wt2, b2,
                                         m2max, m2min, gsum2, gsq2);
  stats_kernel<<<1, 256, 0, stream>>>(gsum2, gsq2, g2, be2, scale2, shift2, 256);
  final_kernel<<<512, 256, 0, stream>>>(m2max, m2min, scale2, shift2, out);
}

// Round 9
// 3908.726 us; speedup vs baseline: 1.4709x; 1.0723x over previous
//
#include <hip/hip_runtime.h>
#include <cstdint>
#include <cstddef>

#define B_ 4
#define N_ 16384
#define S_ 2048
#define K_ 32
#define D_ 64
#define C0_ 67
#define C3_ 256
#define P_ (B_*S_*K_)           // 262144 pixels
#define FEAT_OFF 24576          // B*3*S
#define SEED_OFF (24576 + B_*C3_*S_)

// ---------------------------------------------------------------------------
// FPS: R13 = R12 (proven: 2810us, total 4191us) + two cuts:
//  (a) DPP wave-max reduce: row_shr:1/2/4/8 + row_bcast:15/31 (6 dependent
//      VALU ops, ~60cyc) replaces 6 __shfl_xor (~360cyc of serial
//      ds_bpermute). Result lands in lane 63. fmax-exact -> selection
//      bit-identical.
//  (b) new_xyz/d_out coord writes moved OUT of the loop into gather_kernel
//      (pure gather of xyz[fps_idx], runs before ballquery). FPS stores only
//      fps_idx[it]; wave 0 (which gates B1) loses its 6-store burst.
// Kept from R12: value-only scan (max3), LDS fold of 8 partials, lazy index
// recovery via descending rescan + LDS atomicMin (min global index on ties
// == reference first-index argmax), 4-slot s_cand rotation (2-barrier-safe).
// Distance chain bit-matched: d = fma(dz,dz, fma(dy,dy, dx*dx)).
// ---------------------------------------------------------------------------
__device__ __forceinline__ float wave_max_dpp(float v) {
  // 64-lane max; after the sequence lane 63 holds the wave maximum.
  float t;
  t = __int_as_float(__builtin_amdgcn_update_dpp(
      __float_as_int(-1e30f), __float_as_int(v), 0x111, 0xf, 0xf, false));
  v = fmaxf(v, t);   // row_shr:1
  t = __int_as_float(__builtin_amdgcn_update_dpp(
      __float_as_int(-1e30f), __float_as_int(v), 0x112, 0xf, 0xf, false));
  v = fmaxf(v, t);   // row_shr:2
  t = __int_as_float(__builtin_amdgcn_update_dpp(
      __float_as_int(-1e30f), __float_as_int(v), 0x114, 0xf, 0xf, false));
  v = fmaxf(v, t);   // row_shr:4
  t = __int_as_float(__builtin_amdgcn_update_dpp(
      __float_as_int(-1e30f), __float_as_int(v), 0x118, 0xf, 0xf, false));
  v = fmaxf(v, t);   // row_shr:8 -> lanes 15/31/47/63 hold row maxes
  t = __int_as_float(__builtin_amdgcn_update_dpp(
      __float_as_int(-1e30f), __float_as_int(v), 0x142, 0xf, 0xf, false));
  v = fmaxf(v, t);   // row_bcast:15
  t = __int_as_float(__builtin_amdgcn_update_dpp(
      __float_as_int(-1e30f), __float_as_int(v), 0x143, 0xf, 0xf, false));
  v = fmaxf(v, t);   // row_bcast:31 -> lane 63 = full wave max
  return v;
}

__global__ __launch_bounds__(512, 2) void fps_kernel(
    const float* __restrict__ xyz,
    const int* __restrict__ fps_start,
    int* __restrict__ fps_idx)
{
  const int b = blockIdx.x;
  const int tid = threadIdx.x;
  const int lane = tid & 63;
  const int wid = tid >> 6;          // 0..7
  const float* __restrict__ xb = xyz + (size_t)b * 3 * N_;
  constexpr int PTS = N_ / 512;      // 32
  float px[PTS], py[PTS], pz[PTS], dmin[PTS];
#pragma unroll
  for (int i = 0; i < PTS; ++i) {
    int j = i * 512 + tid;
    px[i] = xb[j]; py[i] = xb[N_ + j]; pz[i] = xb[2 * N_ + j];
    dmin[i] = 1e10f;
  }
  __shared__ float s_val[2][8];
  __shared__ int   s_cand[4];
  if (tid == 0) {
    s_cand[0] = 0x7fffffff; s_cand[1] = 0x7fffffff;
    s_cand[2] = 0x7fffffff; s_cand[3] = 0x7fffffff;
  }
  int cur = fps_start[b];
  __syncthreads();

  for (int it = 0; it < S_; ++it) {
    const int buf = it & 1;
    const int cslot = it & 3;
    int cs = __builtin_amdgcn_readfirstlane(cur);
    float cx = xb[cs], cy = xb[N_ + cs], cz = xb[2 * N_ + cs];
    if (tid == 0) {
      fps_idx[b * S_ + it] = cs;
      s_cand[(it + 2) & 3] = 0x7fffffff;   // reset slot for iter it+2 (2-barrier-safe)
    }
    // scan: update dmin, track max VALUE only (pairs -> v_max3_f32)
    float mx = -1e30f;
#pragma unroll
    for (int i = 0; i < PTS; i += 2) {
      float dx0 = __fadd_rn(px[i], -cx);
      float dy0 = __fadd_rn(py[i], -cy);
      float dz0 = __fadd_rn(pz[i], -cz);
      float d0 = fmaf(dz0, dz0, fmaf(dy0, dy0, __fmul_rn(dx0, dx0)));
      float m0 = fminf(dmin[i], d0); dmin[i] = m0;
      float dx1 = __fadd_rn(px[i + 1], -cx);
      float dy1 = __fadd_rn(py[i + 1], -cy);
      float dz1 = __fadd_rn(pz[i + 1], -cz);
      float d1 = fmaf(dz1, dz1, fmaf(dy1, dy1, __fmul_rn(dx1, dx1)));
      float m1 = fminf(dmin[i + 1], d1); dmin[i + 1] = m1;
      mx = fmaxf(fmaxf(m0, m1), mx);       // max3
    }
    // DPP wave max (result in lane 63)
    float wv = wave_max_dpp(mx);
    if (lane == 63) s_val[buf][wid] = wv;
    __syncthreads();                       // B1
    // block max: every thread folds the 8 wave partials (broadcast reads)
    float bmax = fmaxf(fmaxf(fmaxf(s_val[buf][0], s_val[buf][1]),
                             fmaxf(s_val[buf][2], s_val[buf][3])),
                       fmaxf(fmaxf(s_val[buf][4], s_val[buf][5]),
                             fmaxf(s_val[buf][6], s_val[buf][7])));
    // lazy index recovery: only waves holding the max pay the rescan
    if (mx == bmax) {
      int cand = 0x7fffffff;
#pragma unroll
      for (int i = PTS - 1; i >= 0; --i)   // descending: keeps smallest i
        cand = (dmin[i] == bmax) ? (i * 512 + tid) : cand;
      atomicMin(&s_cand[cslot], cand);
    }
    __syncthreads();                       // B2
    cur = s_cand[cslot];
  }
}

// gather: per (b,s) — new_xyz, d_out xyz rows, seed float. Runs after fps,
// before ballquery (which consumes new_xyz). Replaces the per-iteration
// wave-0 store burst inside the FPS loop.
__global__ __launch_bounds__(256) void gather_kernel(
    const float* __restrict__ xyz, const int* __restrict__ seed_inds,
    const int* __restrict__ fps_idx, float* __restrict__ new_xyz,
    float* __restrict__ d_out)
{
  int i = blockIdx.x * 256 + threadIdx.x;      // 0 .. B*S-1
  if (i >= B_ * S_) return;
  int b = i >> 11;                             // i / S_
  int s = i & (S_ - 1);
  int j = fps_idx[i];
  const float* __restrict__ xb = xyz + (size_t)b * 3 * N_;
  float x = xb[j], y = xb[N_ + j], z = xb[2 * N_ + j];
  new_xyz[i * 3 + 0] = x;
  new_xyz[i * 3 + 1] = y;
  new_xyz[i * 3 + 2] = z;
  d_out[(b * 3 + 0) * S_ + s] = x;
  d_out[(b * 3 + 1) * S_ + s] = y;
  d_out[(b * 3 + 2) * S_ + s] = z;
  d_out[SEED_OFF + i] = (float)seed_inds[(size_t)b * N_ + j];
}

// ---------------------------------------------------------------------------
// Ball query: one wave per centroid; first K in-ball indices ascending,
// pad with first hit.
// ---------------------------------------------------------------------------
__global__ __launch_bounds__(256) void ballquery_kernel(
    const float* __restrict__ xyz, const float* __restrict__ new_xyz,
    int* __restrict__ idxo)
{
  const int c = blockIdx.x * 4 + (threadIdx.x >> 6);
  const int lane = threadIdx.x & 63;
  const int b = c >> 11;
  const float* __restrict__ xb = xyz + (size_t)b * 3 * N_;
  float cx = new_xyz[c * 3 + 0], cy = new_xyz[c * 3 + 1], cz = new_xyz[c * 3 + 2];
  float css = __fadd_rn(__fadd_rn(__fmul_rn(cx, cx), __fmul_rn(cy, cy)),
                        __fmul_rn(cz, cz));
  const double rr = 0.3 * 0.3;
  int cnt = 0, first = -1;
  for (int base = 0; base < N_; base += 64) {
    int j = base + lane;
    float x = xb[j], y = xb[N_ + j], z = xb[2 * N_ + j];
    float pss = __fadd_rn(__fadd_rn(__fmul_rn(x, x), __fmul_rn(y, y)),
                          __fmul_rn(z, z));
    float dot = __fadd_rn(__fadd_rn(__fmul_rn(cx, x), __fmul_rn(cy, y)),
                          __fmul_rn(cz, z));
    float d = __fadd_rn(__fadd_rn(__fmul_rn(-2.f, dot), css), pss);
    bool in = (double)d <= rr;
    unsigned long long m = __ballot(in);
    if (m) {
      if (first < 0) first = base + (__ffsll((long long)m) - 1);
      int rank = (int)__popcll(m & ((1ull << lane) - 1ull));
      int pos = cnt + rank;
      if (in && pos < K_) idxo[(size_t)c * K_ + pos] = j;
      cnt += (int)__popcll(m);
      if (cnt >= K_) break;
    }
  }
  for (int p = cnt + lane; p < K_; p += 64) idxo[(size_t)c * K_ + p] = first;
}

// ---------------------------------------------------------------------------
// points (B,D,N) -> (B,N,D) (only used when ws_size permits).
// ---------------------------------------------------------------------------
__global__ __launch_bounds__(256) void transpose_pts_kernel(
    const float* __restrict__ pts, float* __restrict__ pts_t)
{
  __shared__ float tile[64][65];
  const int blk = blockIdx.x;
  const int b = blk >> 8;
  const int n0 = (blk & 255) * 64;
  const int tx = threadIdx.x & 63, ty = threadIdx.x >> 6;
#pragma unroll
  for (int r = 0; r < 16; ++r) {
    int d = r * 4 + ty;
    tile[d][tx] = pts[((size_t)b * D_ + d) * N_ + n0 + tx];
  }
  __syncthreads();
#pragma unroll
  for (int r = 0; r < 16; ++r) {
    int nl = r * 4 + ty;
    pts_t[((size_t)b * N_ + n0 + nl) * D_ + tx] = tile[tx][nl];
  }
}

__global__ void transpose_w_kernel(
    const float* __restrict__ W0, const float* __restrict__ W1,
    const float* __restrict__ W2, float* __restrict__ wt0,
    float* __restrict__ wt1, float* __restrict__ wt2)
{
  int i = blockIdx.x * 256 + threadIdx.x;
  if (i < 128 * 67) { int co = i / 67, ci = i % 67; wt0[ci * 128 + co] = W0[i]; }
  int i1 = i - 128 * 67;
  if (i1 >= 0 && i1 < 128 * 128) { int co = i1 >> 7, ci = i1 & 127; wt1[ci * 128 + co] = W1[i1]; }
  int i2 = i1 - 128 * 128;
  if (i2 >= 0 && i2 < 256 * 128) { int co = i2 >> 7, ci = i2 & 127; wt2[ci * 256 + co] = W2[i2]; }
}

// ---------------------------------------------------------------------------
// Shared device helpers for the recompute passes.
// ---------------------------------------------------------------------------
__device__ __forceinline__ void stage_x0(
    int gp0, int tid, const float* __restrict__ xyz,
    const float* __restrict__ pts, const float* __restrict__ pts_t, int use_pt,
    const float* __restrict__ new_xyz, const int* __restrict__ idxo,
    float* __restrict__ bufA)
{
  int pxl = tid >> 2, q = tid & 3;
  int gp = gp0 + pxl;
  int b = gp >> 16;
  int s = (gp >> 5) & (S_ - 1);
  int j = idxo[gp];
  if (use_pt) {
    const float* src = pts_t + ((size_t)b * N_ + j) * 64 + q * 16;
#pragma unroll
    for (int v = 0; v < 4; ++v) {
      float4 f = *(const float4*)(src + v * 4);
      int c = 3 + q * 16 + v * 4;
      bufA[(c + 0) * 72 + pxl] = f.x;
      bufA[(c + 1) * 72 + pxl] = f.y;
      bufA[(c + 2) * 72 + pxl] = f.z;
      bufA[(c + 3) * 72 + pxl] = f.w;
    }
  } else {
    const float* src = pts + ((size_t)b * D_ + q * 16) * N_ + j;
#pragma unroll
    for (int v = 0; v < 16; ++v)
      bufA[(3 + q * 16 + v) * 72 + pxl] = src[(size_t)v * N_];
  }
  if (q == 0) {
    const float* xb = xyz + (size_t)b * 3 * N_;
    int c3 = (b * S_ + s) * 3;
    bufA[0 * 72 + pxl] = xb[j] - new_xyz[c3 + 0];
    bufA[1 * 72 + pxl] = xb[N_ + j] - new_xyz[c3 + 1];
    bufA[2 * 72 + pxl] = xb[2 * N_ + j] - new_xyz[c3 + 2];
  }
}

// 8-cout conv micro-tile: acc[4 px][8 co] += buf[ci][pg*4..] * w[ci][cog*8..]
template<int CIN>
__device__ __forceinline__ void conv8(
    const float* __restrict__ buf, const float* __restrict__ wrow, int pg,
    float acc[4][8])
{
  for (int ci = 0; ci < CIN; ++ci) {
    float4 x4 = *(const float4*)&buf[ci * 72 + pg * 4];
    float4 wa = *(const float4*)&wrow[ci * 128];
    float4 wb = *(const float4*)&wrow[ci * 128 + 4];
    float xr[4] = {x4.x, x4.y, x4.z, x4.w};
    float wv[8] = {wa.x, wa.y, wa.z, wa.w, wb.x, wb.y, wb.z, wb.w};
#pragma unroll
    for (int i = 0; i < 4; ++i)
#pragma unroll
      for (int j = 0; j < 8; ++j) acc[i][j] = fmaf(xr[i], wv[j], acc[i][j]);
  }
}

// ---------------------------------------------------------------------------
// passA: conv0 stats only (no y0 store).
// ---------------------------------------------------------------------------
__global__ __launch_bounds__(256) void passA_kernel(
    const float* __restrict__ xyz, const float* __restrict__ pts,
    const float* __restrict__ pts_t, int use_pt,
    const float* __restrict__ new_xyz, const int* __restrict__ idxo,
    const float* __restrict__ wt0, const float* __restrict__ b0,
    float* __restrict__ gsum, float* __restrict__ gsq)
{
  __shared__ __align__(16) float bufA[C0_ * 72];
  __shared__ float s_sum[4][128], s_sq[4][128];
  const int tid = threadIdx.x;
  const int lane = tid & 63, wid = tid >> 6;
  const int cog = tid & 15, pg = tid >> 4;
  float bias[8];
#pragma unroll
  for (int j = 0; j < 8; ++j) bias[j] = b0[cog * 8 + j];
  float ssum[8], ssq[8];
#pragma unroll
  for (int j = 0; j < 8; ++j) { ssum[j] = 0.f; ssq[j] = 0.f; }

  for (int t = 0; t < 4; ++t) {
    const int gp0 = (blockIdx.x * 4 + t) * 64;
    __syncthreads();
    stage_x0(gp0, tid, xyz, pts, pts_t, use_pt, new_xyz, idxo, bufA);
    __syncthreads();
    float acc[4][8];
#pragma unroll
    for (int i = 0; i < 4; ++i)
#pragma unroll
      for (int j = 0; j < 8; ++j) acc[i][j] = 0.f;
    conv8<C0_>(bufA, wt0 + cog * 8, pg, acc);
#pragma unroll
    for (int i = 0; i < 4; ++i)
#pragma unroll
      for (int j = 0; j < 8; ++j) {
        float y = acc[i][j] + bias[j];
        ssum[j] += y;
        ssq[j] = fmaf(y, y, ssq[j]);
      }
  }
#pragma unroll
  for (int j = 0; j < 8; ++j) {
    float v = ssum[j];
    v += __shfl_xor(v, 16, 64); v += __shfl_xor(v, 32, 64);
    float q = ssq[j];
    q += __shfl_xor(q, 16, 64); q += __shfl_xor(q, 32, 64);
    if (lane < 16) { s_sum[wid][lane * 8 + j] = v; s_sq[wid][lane * 8 + j] = q; }
  }
  __syncthreads();
  if (tid < 128) {
    float v = s_sum[0][tid] + s_sum[1][tid] + s_sum[2][tid] + s_sum[3][tid];
    float q = s_sq[0][tid] + s_sq[1][tid] + s_sq[2][tid] + s_sq[3][tid];
    atomicAdd(&gsum[tid], v);
    atomicAdd(&gsq[tid], q);
  }
}

// ---------------------------------------------------------------------------
// passB: recompute conv0 -> BN0+ReLU -> conv1 stats (no y1 store).
// ---------------------------------------------------------------------------
__global__ __launch_bounds__(256) void passB_kernel(
    const float* __restrict__ xyz, const float* __restrict__ pts,
    const float* __restrict__ pts_t, int use_pt,
    const float* __restrict__ new_xyz, const int* __restrict__ idxo,
    const float* __restrict__ wt0, const float* __restrict__ b0,
    const float* __restrict__ scale0, const float* __restrict__ shift0,
    const float* __restrict__ wt1, const float* __restrict__ b1,
    float* __restrict__ gsum, float* __restrict__ gsq)
{
  __shared__ __align__(16) float bufA[C0_ * 72];
  __shared__ __align__(16) float bufB[128 * 72];
  __shared__ float s_sum[4][128], s_sq[4][128];
  const int tid = threadIdx.x;
  const int lane = tid & 63, wid = tid >> 6;
  const int cog = tid & 15, pg = tid >> 4;
  float bias0[8], bias1[8], sc0[8], sh0[8];
#pragma unroll
  for (int j = 0; j < 8; ++j) {
    bias0[j] = b0[cog * 8 + j];
    bias1[j] = b1[cog * 8 + j];
    sc0[j] = scale0[cog * 8 + j];
    sh0[j] = shift0[cog * 8 + j];
  }
  float ssum[8], ssq[8];
#pragma unroll
  for (int j = 0; j < 8; ++j) { ssum[j] = 0.f; ssq[j] = 0.f; }

  for (int t = 0; t < 4; ++t) {
    const int gp0 = (blockIdx.x * 4 + t) * 64;
    __syncthreads();
    stage_x0(gp0, tid, xyz, pts, pts_t, use_pt, new_xyz, idxo, bufA);
    __syncthreads();
    float acc[4][8];
#pragma unroll
    for (int i = 0; i < 4; ++i)
#pragma unroll
      for (int j = 0; j < 8; ++j) acc[i][j] = 0.f;
    conv8<C0_>(bufA, wt0 + cog * 8, pg, acc);
#pragma unroll
    for (int i = 0; i < 4; ++i)
#pragma unroll
      for (int j = 0; j < 8; ++j) {
        float y = acc[i][j] + bias0[j];
        bufB[(cog * 8 + j) * 72 + pg * 4 + i] = fmaxf(0.f, fmaf(y, sc0[j], sh0[j]));
      }
    __syncthreads();
#pragma unroll
    for (int i = 0; i < 4; ++i)
#pragma unroll
      for (int j = 0; j < 8; ++j) acc[i][j] = 0.f;
    conv8<128>(bufB, wt1 + cog * 8, pg, acc);
#pragma unroll
    for (int i = 0; i < 4; ++i)
#pragma unroll
      for (int j = 0; j < 8; ++j) {
        float y = acc[i][j] + bias1[j];
        ssum[j] += y;
        ssq[j] = fmaf(y, y, ssq[j]);
      }
  }
#pragma unroll
  for (int j = 0; j < 8; ++j) {
    float v = ssum[j];
    v += __shfl_xor(v, 16, 64); v += __shfl_xor(v, 32, 64);
    float q = ssq[j];
    q += __shfl_xor(q, 16, 64); q += __shfl_xor(q, 32, 64);
    if (lane < 16) { s_sum[wid][lane * 8 + j] = v; s_sq[wid][lane * 8 + j] = q; }
  }
  __syncthreads();
  if (tid < 128) {
    float v = s_sum[0][tid] + s_sum[1][tid] + s_sum[2][tid] + s_sum[3][tid];
    float q = s_sq[0][tid] + s_sq[1][tid] + s_sq[2][tid] + s_sq[3][tid];
    atomicAdd(&gsum[tid], v);
    atomicAdd(&gsq[tid], q);
  }
}

// ---------------------------------------------------------------------------
// passC: recompute conv0->BN0->conv1->BN1->conv2; emit per-centroid max/min
// of y2 (BN2+ReLU is monotone affine) + conv2 stats. Never stores y2.
// ---------------------------------------------------------------------------
__global__ __launch_bounds__(256) void passC_kernel(
    const float* __restrict__ xyz, const float* __restrict__ pts,
    const float* __restrict__ pts_t, int use_pt,
    const float* __restrict__ new_xyz, const int* __restrict__ idxo,
    const float* __restrict__ wt0, const float* __restrict__ b0,
    const float* __restrict__ scale0, const float* __restrict__ shift0,
    const float* __restrict__ wt1, const float* __restrict__ b1,
    const float* __restrict__ scale1, const float* __restrict__ shift1,
    const float* __restrict__ wt2, const float* __restrict__ b2,
    float* __restrict__ m2max, float* __restrict__ m2min,
    float* __restrict__ gsum, float* __restrict__ gsq)
{
  __shared__ __align__(16) float bufA[128 * 72];   // x0 (67 rows) then x2 (128 rows)
  __shared__ __align__(16) float bufB[128 * 72];   // x1
  __shared__ float s_m[4 * 256], s_n[4 * 256];
  __shared__ float s_sum[4][256], s_sq[4][256];
  const int tid = threadIdx.x;
  const int lane = tid & 63, wid = tid >> 6;
  const int cog = tid & 15, pg = tid >> 4;
  const int co0 = cog * 16;
  float bias0[8], bias1[8], sc0[8], sh0[8], sc1[8], sh1[8];
#pragma unroll
  for (int j = 0; j < 8; ++j) {
    bias0[j] = b0[cog * 8 + j];
    bias1[j] = b1[cog * 8 + j];
    sc0[j] = scale0[cog * 8 + j];
    sh0[j] = shift0[cog * 8 + j];
    sc1[j] = scale1[cog * 8 + j];
    sh1[j] = shift1[cog * 8 + j];
  }
  float bias2[16];
#pragma unroll
  for (int j = 0; j < 16; ++j) bias2[j] = b2[co0 + j];
  float ssum[16], ssq[16];
#pragma unroll
  for (int j = 0; j < 16; ++j) { ssum[j] = 0.f; ssq[j] = 0.f; }

  for (int t = 0; t < 4; ++t) {
    const int gp0 = (blockIdx.x * 4 + t) * 64;
    __syncthreads();
    stage_x0(gp0, tid, xyz, pts, pts_t, use_pt, new_xyz, idxo, bufA);
    __syncthreads();
    // conv0 -> x1
    {
      float acc[4][8];
#pragma unroll
      for (int i = 0; i < 4; ++i)
#pragma unroll
        for (int j = 0; j < 8; ++j) acc[i][j] = 0.f;
      conv8<C0_>(bufA, wt0 + cog * 8, pg, acc);
#pragma unroll
      for (int i = 0; i < 4; ++i)
#pragma unroll
        for (int j = 0; j < 8; ++j) {
          float y = acc[i][j] + bias0[j];
          bufB[(cog * 8 + j) * 72 + pg * 4 + i] = fmaxf(0.f, fmaf(y, sc0[j], sh0[j]));
        }
    }
    __syncthreads();                 // all conv0 reads of bufA done
    // conv1 -> x2 (into bufA)
    {
      float acc[4][8];
#pragma unroll
      for (int i = 0; i < 4; ++i)
#pragma unroll
        for (int j = 0; j < 8; ++j) acc[i][j] = 0.f;
      conv8<128>(bufB, wt1 + cog * 8, pg, acc);
#pragma unroll
      for (int i = 0; i < 4; ++i)
#pragma unroll
        for (int j = 0; j < 8; ++j) {
          float y = acc[i][j] + bias1[j];
          bufA[(cog * 8 + j) * 72 + pg * 4 + i] = fmaxf(0.f, fmaf(y, sc1[j], sh1[j]));
        }
    }
    __syncthreads();
    // conv2 -> stats + per-centroid max/min
    {
      float acc[4][16];
#pragma unroll
      for (int i = 0; i < 4; ++i)
#pragma unroll
        for (int j = 0; j < 16; ++j) acc[i][j] = 0.f;
      const float* wrow = wt2 + co0;
      for (int ci = 0; ci < 128; ++ci) {
        float4 x4 = *(const float4*)&bufA[ci * 72 + pg * 4];
        float xr[4] = {x4.x, x4.y, x4.z, x4.w};
        float wv[16];
#pragma unroll
        for (int w4 = 0; w4 < 4; ++w4) {
          float4 wf = *(const float4*)&wrow[ci * 256 + w4 * 4];
          wv[w4 * 4 + 0] = wf.x; wv[w4 * 4 + 1] = wf.y;
          wv[w4 * 4 + 2] = wf.z; wv[w4 * 4 + 3] = wf.w;
        }
#pragma unroll
        for (int i = 0; i < 4; ++i)
#pragma unroll
          for (int j = 0; j < 16; ++j) acc[i][j] = fmaf(xr[i], wv[j], acc[i][j]);
      }
      float mx[16], mn[16];
#pragma unroll
      for (int j = 0; j < 16; ++j) { mx[j] = -3.4e38f; mn[j] = 3.4e38f; }
#pragma unroll
      for (int i = 0; i < 4; ++i)
#pragma unroll
        for (int j = 0; j < 16; ++j) {
          float y = acc[i][j] + bias2[j];
          ssum[j] += y;
          ssq[j] = fmaf(y, y, ssq[j]);
          mx[j] = fmaxf(mx[j], y);
          mn[j] = fminf(mn[j], y);
        }
#pragma unroll
      for (int j = 0; j < 16; ++j) {
        float a = mx[j];
        a = fmaxf(a, __shfl_xor(a, 16, 64)); a = fmaxf(a, __shfl_xor(a, 32, 64));
        float c = mn[j];
        c = fminf(c, __shfl_xor(c, 16, 64)); c = fminf(c, __shfl_xor(c, 32, 64));
        if (lane < 16) {
          s_m[wid * 256 + lane * 16 + j] = a;
          s_n[wid * 256 + lane * 16 + j] = c;
        }
      }
      __syncthreads();
      {
        int co = tid;
        size_t bsA = (size_t)(gp0 >> 5);   // global (b*S+s) of first centroid
        m2max[bsA * 256 + co]       = fmaxf(s_m[co], s_m[256 + co]);
        m2max[(bsA + 1) * 256 + co] = fmaxf(s_m[512 + co], s_m[768 + co]);
        m2min[bsA * 256 + co]       = fminf(s_n[co], s_n[256 + co]);
        m2min[(bsA + 1) * 256 + co] = fminf(s_n[512 + co], s_n[768 + co]);
      }
    }
  }
#pragma unroll
  for (int j = 0; j < 16; ++j) {
    float v = ssum[j];
    v += __shfl_xor(v, 16, 64); v += __shfl_xor(v, 32, 64);
    float q = ssq[j];
    q += __shfl_xor(q, 16, 64); q += __shfl_xor(q, 32, 64);
    if (lane < 16) { s_sum[wid][lane * 16 + j] = v; s_sq[wid][lane * 16 + j] = q; }
  }
  __syncthreads();
  {
    int co = tid;
    float v = s_sum[0][co] + s_sum[1][co] + s_sum[2][co] + s_sum[3][co];
    float q = s_sq[0][co] + s_sq[1][co] + s_sq[2][co] + s_sq[3][co];
    atomicAdd(&gsum[co], v);
    atomicAdd(&gsq[co], q);
  }
}

__global__ void stats_kernel(
    const float* __restrict__ gsum, const float* __restrict__ gsq,
    const float* __restrict__ g, const float* __restrict__ be,
    float* __restrict__ scale, float* __restrict__ shift, int C)
{
  int c = threadIdx.x;
  if (c >= C) return;
  const float invP = 1.0f / (float)P_;   // P = 2^18, exact division
  float mean = gsum[c] * invP;
  float var = fmaxf(gsq[c] * invP - mean * mean, 0.f);
  float r = 1.0f / sqrtf(var + 1e-5f);
  float sc = g[c] * r;
  scale[c] = sc;
  shift[c] = be[c] - mean * sc;
}

// feat[b][c][s] = relu(scale2*(scale2>=0 ? max : min) + shift2), transposed.
__global__ __launch_bounds__(256) void final_kernel(
    const float* __restrict__ m2max, const float* __restrict__ m2min,
    const float* __restrict__ scale2, const float* __restrict__ shift2,
    float* __restrict__ d_out)
{
  __shared__ float tmx[64][65], tmn[64][65];
  const int blk = blockIdx.x;
  const int b = blk >> 7;
  const int st = (blk >> 2) & 31;
  const int ct = blk & 3;
  const int s0 = st * 64, c0 = ct * 64;
  const int tx = threadIdx.x & 63, ty = threadIdx.x >> 6;
#pragma unroll
  for (int r = 0; r < 16; ++r) {
    int sl = r * 4 + ty;
    size_t src = ((size_t)(b * S_ + s0 + sl)) * 256 + c0 + tx;
    tmx[sl][tx] = m2max[src];
    tmn[sl][tx] = m2min[src];
  }
  __syncthreads();
#pragma unroll
  for (int r = 0; r < 16; ++r) {
    int cl = r * 4 + ty;
    int c = c0 + cl;
    float sc = scale2[c], sh = shift2[c];
    float m = (sc >= 0.f) ? tmx[tx][cl] : tmn[tx][cl];
    d_out[FEAT_OFF + ((size_t)(b * C3_ + c)) * S_ + s0 + tx] =
        fmaxf(0.f, fmaf(m, sc, sh));
  }
}

// ---------------------------------------------------------------------------
extern "C" void kernel_launch(void* const* d_in, const int* in_sizes, int n_in,
                              void* d_out_v, int out_size, void* d_ws,
                              size_t ws_size, hipStream_t stream)
{
  (void)in_sizes; (void)n_in; (void)out_size;
  const float* xyz = (const float*)d_in[0];
  const float* pts = (const float*)d_in[1];
  const int* seed = (const int*)d_in[2];
  const int* fstart = (const int*)d_in[3];
  const float* W0 = (const float*)d_in[4];
  const float* b0 = (const float*)d_in[5];
  const float* g0 = (const float*)d_in[6];
  const float* be0 = (const float*)d_in[7];
  const float* W1 = (const float*)d_in[8];
  const float* b1 = (const float*)d_in[9];
  const float* g1 = (const float*)d_in[10];
  const float* be1 = (const float*)d_in[11];
  const float* W2 = (const float*)d_in[12];
  const float* b2 = (const float*)d_in[13];
  const float* g2 = (const float*)d_in[14];
  const float* be2 = (const float*)d_in[15];
  float* out = (float*)d_out_v;
  char* ws = (char*)d_ws;

  size_t off = 0;
  auto alloc = [&](size_t bytes) -> void* {
    off = (off + 255) & ~(size_t)255;
    void* p = ws + off;
    off += bytes;
    return p;
  };
  // Compact layout: ~18 MB (+16 MB pts_t only if ws_size allows).
  int*   fps_idx = (int*)alloc((size_t)B_ * S_ * 4);
  float* new_xyz = (float*)alloc((size_t)B_ * S_ * 3 * 4);
  int*   idxo    = (int*)alloc((size_t)B_ * S_ * K_ * 4);
  float* m2max   = (float*)alloc((size_t)B_ * S_ * 256 * 4);
  float* m2min   = (float*)alloc((size_t)B_ * S_ * 256 * 4);
  float* stats   = (float*)alloc(1024 * 4);
  float* scsh    = (float*)alloc(1024 * 4);
  float* wt0     = (float*)alloc((size_t)67 * 128 * 4);
  float* wt1     = (float*)alloc((size_t)128 * 128 * 4);
  float* wt2     = (float*)alloc((size_t)128 * 256 * 4);
  const int use_pt = (ws_size >= (off + (size_t)B_ * N_ * D_ * 4 + (1u << 20))) ? 1 : 0;
  float* pts_t   = use_pt ? (float*)alloc((size_t)B_ * N_ * D_ * 4) : (float*)ws;

  float* gsum0 = stats, *gsq0 = stats + 128;
  float* gsum1 = stats + 256, *gsq1 = stats + 384;
  float* gsum2 = stats + 512, *gsq2 = stats + 768;
  float* scale0 = scsh, *shift0 = scsh + 128;
  float* scale1 = scsh + 256, *shift1 = scsh + 384;
  float* scale2 = scsh + 512, *shift2 = scsh + 768;

  hipMemsetAsync(stats, 0, 1024 * 4, stream);
  transpose_w_kernel<<<226, 256, 0, stream>>>(W0, W1, W2, wt0, wt1, wt2);
  if (use_pt)
    transpose_pts_kernel<<<B_ * 256, 256, 0, stream>>>(pts, pts_t);
  fps_kernel<<<B_, 512, 0, stream>>>(xyz, fstart, fps_idx);
  gather_kernel<<<(B_ * S_ + 255) / 256, 256, 0, stream>>>(xyz, seed, fps_idx,
                                                           new_xyz, out);
  ballquery_kernel<<<B_ * S_ / 4, 256, 0, stream>>>(xyz, new_xyz, idxo);
  passA_kernel<<<1024, 256, 0, stream>>>(xyz, pts, pts_t, use_pt, new_xyz, idxo,
                                         wt0, b0, gsum0, gsq0);
  stats_kernel<<<1, 128, 0, stream>>>(gsum0, gsq0, g0, be0, scale0, shift0, 128);
  passB_kernel<<<1024, 256, 0, stream>>>(xyz, pts, pts_t, use_pt, new_xyz, idxo,
                                         wt0, b0, scale0, shift0, wt1, b1,
                                         gsum1, gsq1);
  stats_kernel<<<1, 128, 0, stream>>>(gsum1, gsq1, g1, be1, scale1, shift1, 128);
  passC_kernel<<<1024, 256, 0, stream>>>(xyz, pts, pts_t, use_pt, new_xyz, idxo,
                                         wt0, b0, scale0, shift0, wt1, b1,
                                         scale1, shift1, wt2, b2,
                                         m2max, m2min, gsum2, gsq2);
  stats_kernel<<<1, 256, 0, stream>>>(gsum2, gsq2, g2, be2, scale2, shift2, 256);
  final_kernel<<<512, 256, 0, stream>>>(m2max, m2min, scale2, shift2, out);
}

// Round 10
// 3813.139 us; speedup vs baseline: 1.5078x; 1.0251x over previous
//
#include <hip/hip_runtime.h>
#include <cstdint>
#include <cstddef>

#define B_ 4
#define N_ 16384
#define S_ 2048
#define K_ 32
#define D_ 64
#define C0_ 67
#define C3_ 256
#define P_ (B_*S_*K_)           // 262144 pixels
#define FEAT_OFF 24576          // B*3*S
#define SEED_OFF (24576 + B_*C3_*S_)

// ---------------------------------------------------------------------------
// FPS: R13 structure (proven 2550us): value-only scan (max3), DPP wave max,
// LDS fold of 8 partials, lazy index recovery (descending rescan + LDS
// atomicMin; min global index on ties == reference first-index argmax),
// 4-slot s_cand rotation. Distance chain bit-matched:
//   d = fma(dz,dz, fma(dy,dy, dx*dx))
// ---------------------------------------------------------------------------
__device__ __forceinline__ float wave_max_dpp(float v) {
  // 64-lane max; after the sequence lane 63 holds the wave maximum.
  float t;
  t = __int_as_float(__builtin_amdgcn_update_dpp(
      __float_as_int(-1e30f), __float_as_int(v), 0x111, 0xf, 0xf, false));
  v = fmaxf(v, t);   // row_shr:1
  t = __int_as_float(__builtin_amdgcn_update_dpp(
      __float_as_int(-1e30f), __float_as_int(v), 0x112, 0xf, 0xf, false));
  v = fmaxf(v, t);   // row_shr:2
  t = __int_as_float(__builtin_amdgcn_update_dpp(
      __float_as_int(-1e30f), __float_as_int(v), 0x114, 0xf, 0xf, false));
  v = fmaxf(v, t);   // row_shr:4
  t = __int_as_float(__builtin_amdgcn_update_dpp(
      __float_as_int(-1e30f), __float_as_int(v), 0x118, 0xf, 0xf, false));
  v = fmaxf(v, t);   // row_shr:8 -> lanes 15/31/47/63 hold row maxes
  t = __int_as_float(__builtin_amdgcn_update_dpp(
      __float_as_int(-1e30f), __float_as_int(v), 0x142, 0xf, 0xf, false));
  v = fmaxf(v, t);   // row_bcast:15
  t = __int_as_float(__builtin_amdgcn_update_dpp(
      __float_as_int(-1e30f), __float_as_int(v), 0x143, 0xf, 0xf, false));
  v = fmaxf(v, t);   // row_bcast:31 -> lane 63 = full wave max
  return v;
}

__global__ __launch_bounds__(512, 2) void fps_kernel(
    const float* __restrict__ xyz,
    const int* __restrict__ fps_start,
    int* __restrict__ fps_idx)
{
  const int b = blockIdx.x;
  const int tid = threadIdx.x;
  const int lane = tid & 63;
  const int wid = tid >> 6;          // 0..7
  const float* __restrict__ xb = xyz + (size_t)b * 3 * N_;
  constexpr int PTS = N_ / 512;      // 32
  float px[PTS], py[PTS], pz[PTS], dmin[PTS];
#pragma unroll
  for (int i = 0; i < PTS; ++i) {
    int j = i * 512 + tid;
    px[i] = xb[j]; py[i] = xb[N_ + j]; pz[i] = xb[2 * N_ + j];
    dmin[i] = 1e10f;
  }
  __shared__ float s_val[2][8];
  __shared__ int   s_cand[4];
  if (tid == 0) {
    s_cand[0] = 0x7fffffff; s_cand[1] = 0x7fffffff;
    s_cand[2] = 0x7fffffff; s_cand[3] = 0x7fffffff;
  }
  int cur = fps_start[b];
  __syncthreads();

  for (int it = 0; it < S_; ++it) {
    const int buf = it & 1;
    const int cslot = it & 3;
    int cs = __builtin_amdgcn_readfirstlane(cur);
    float cx = xb[cs], cy = xb[N_ + cs], cz = xb[2 * N_ + cs];
    if (tid == 0) {
      fps_idx[b * S_ + it] = cs;
      s_cand[(it + 2) & 3] = 0x7fffffff;   // reset slot for iter it+2 (2-barrier-safe)
    }
    // scan: update dmin, track max VALUE only (pairs -> v_max3_f32)
    float mx = -1e30f;
#pragma unroll
    for (int i = 0; i < PTS; i += 2) {
      float dx0 = __fadd_rn(px[i], -cx);
      float dy0 = __fadd_rn(py[i], -cy);
      float dz0 = __fadd_rn(pz[i], -cz);
      float d0 = fmaf(dz0, dz0, fmaf(dy0, dy0, __fmul_rn(dx0, dx0)));
      float m0 = fminf(dmin[i], d0); dmin[i] = m0;
      float dx1 = __fadd_rn(px[i + 1], -cx);
      float dy1 = __fadd_rn(py[i + 1], -cy);
      float dz1 = __fadd_rn(pz[i + 1], -cz);
      float d1 = fmaf(dz1, dz1, fmaf(dy1, dy1, __fmul_rn(dx1, dx1)));
      float m1 = fminf(dmin[i + 1], d1); dmin[i + 1] = m1;
      mx = fmaxf(fmaxf(m0, m1), mx);       // max3
    }
    // DPP wave max (result in lane 63)
    float wv = wave_max_dpp(mx);
    if (lane == 63) s_val[buf][wid] = wv;
    __syncthreads();                       // B1
    // block max: every thread folds the 8 wave partials (broadcast reads)
    float bmax = fmaxf(fmaxf(fmaxf(s_val[buf][0], s_val[buf][1]),
                             fmaxf(s_val[buf][2], s_val[buf][3])),
                       fmaxf(fmaxf(s_val[buf][4], s_val[buf][5]),
                             fmaxf(s_val[buf][6], s_val[buf][7])));
    // lazy index recovery: only waves holding the max pay the rescan
    if (mx == bmax) {
      int cand = 0x7fffffff;
#pragma unroll
      for (int i = PTS - 1; i >= 0; --i)   // descending: keeps smallest i
        cand = (dmin[i] == bmax) ? (i * 512 + tid) : cand;
      atomicMin(&s_cand[cslot], cand);
    }
    __syncthreads();                       // B2
    cur = s_cand[cslot];
  }
}

// gather: per (b,s) — new_xyz, d_out xyz rows, seed float. Runs after fps,
// before ballquery (which consumes new_xyz).
__global__ __launch_bounds__(256) void gather_kernel(
    const float* __restrict__ xyz, const int* __restrict__ seed_inds,
    const int* __restrict__ fps_idx, float* __restrict__ new_xyz,
    float* __restrict__ d_out)
{
  int i = blockIdx.x * 256 + threadIdx.x;      // 0 .. B*S-1
  if (i >= B_ * S_) return;
  int b = i >> 11;                             // i / S_
  int s = i & (S_ - 1);
  int j = fps_idx[i];
  const float* __restrict__ xb = xyz + (size_t)b * 3 * N_;
  float x = xb[j], y = xb[N_ + j], z = xb[2 * N_ + j];
  new_xyz[i * 3 + 0] = x;
  new_xyz[i * 3 + 1] = y;
  new_xyz[i * 3 + 2] = z;
  d_out[(b * 3 + 0) * S_ + s] = x;
  d_out[(b * 3 + 1) * S_ + s] = y;
  d_out[(b * 3 + 2) * S_ + s] = z;
  d_out[SEED_OFF + i] = (float)seed_inds[(size_t)b * N_ + j];
}

// ---------------------------------------------------------------------------
// Ball query: one wave per centroid; first K in-ball indices ascending,
// pad with first hit.
// ---------------------------------------------------------------------------
__global__ __launch_bounds__(256) void ballquery_kernel(
    const float* __restrict__ xyz, const float* __restrict__ new_xyz,
    int* __restrict__ idxo)
{
  const int c = blockIdx.x * 4 + (threadIdx.x >> 6);
  const int lane = threadIdx.x & 63;
  const int b = c >> 11;
  const float* __restrict__ xb = xyz + (size_t)b * 3 * N_;
  float cx = new_xyz[c * 3 + 0], cy = new_xyz[c * 3 + 1], cz = new_xyz[c * 3 + 2];
  float css = __fadd_rn(__fadd_rn(__fmul_rn(cx, cx), __fmul_rn(cy, cy)),
                        __fmul_rn(cz, cz));
  const double rr = 0.3 * 0.3;
  int cnt = 0, first = -1;
  for (int base = 0; base < N_; base += 64) {
    int j = base + lane;
    float x = xb[j], y = xb[N_ + j], z = xb[2 * N_ + j];
    float pss = __fadd_rn(__fadd_rn(__fmul_rn(x, x), __fmul_rn(y, y)),
                          __fmul_rn(z, z));
    float dot = __fadd_rn(__fadd_rn(__fmul_rn(cx, x), __fmul_rn(cy, y)),
                          __fmul_rn(cz, z));
    float d = __fadd_rn(__fadd_rn(__fmul_rn(-2.f, dot), css), pss);
    bool in = (double)d <= rr;
    unsigned long long m = __ballot(in);
    if (m) {
      if (first < 0) first = base + (__ffsll((long long)m) - 1);
      int rank = (int)__popcll(m & ((1ull << lane) - 1ull));
      int pos = cnt + rank;
      if (in && pos < K_) idxo[(size_t)c * K_ + pos] = j;
      cnt += (int)__popcll(m);
      if (cnt >= K_) break;
    }
  }
  for (int p = cnt + lane; p < K_; p += 64) idxo[(size_t)c * K_ + p] = first;
}

// ---------------------------------------------------------------------------
// points (B,D,N) -> (B,N,D) (only used when ws_size permits).
// ---------------------------------------------------------------------------
__global__ __launch_bounds__(256) void transpose_pts_kernel(
    const float* __restrict__ pts, float* __restrict__ pts_t)
{
  __shared__ float tile[64][65];
  const int blk = blockIdx.x;
  const int b = blk >> 8;
  const int n0 = (blk & 255) * 64;
  const int tx = threadIdx.x & 63, ty = threadIdx.x >> 6;
#pragma unroll
  for (int r = 0; r < 16; ++r) {
    int d = r * 4 + ty;
    tile[d][tx] = pts[((size_t)b * D_ + d) * N_ + n0 + tx];
  }
  __syncthreads();
#pragma unroll
  for (int r = 0; r < 16; ++r) {
    int nl = r * 4 + ty;
    pts_t[((size_t)b * N_ + n0 + nl) * D_ + tx] = tile[tx][nl];
  }
}

__global__ void transpose_w_kernel(
    const float* __restrict__ W0, const float* __restrict__ W1,
    const float* __restrict__ W2, float* __restrict__ wt0,
    float* __restrict__ wt1, float* __restrict__ wt2)
{
  int i = blockIdx.x * 256 + threadIdx.x;
  if (i < 128 * 67) { int co = i / 67, ci = i % 67; wt0[ci * 128 + co] = W0[i]; }
  int i1 = i - 128 * 67;
  if (i1 >= 0 && i1 < 128 * 128) { int co = i1 >> 7, ci = i1 & 127; wt1[ci * 128 + co] = W1[i1]; }
  int i2 = i1 - 128 * 128;
  if (i2 >= 0 && i2 < 256 * 128) { int co = i2 >> 7, ci = i2 & 127; wt2[ci * 256 + co] = W2[i2]; }
}

// ---------------------------------------------------------------------------
// Shared device helpers for the recompute passes. STR = LDS row stride
// (72 for passA/passB; 70 for passC to fit 2 blocks/CU).
// ---------------------------------------------------------------------------
template<int STR>
__device__ __forceinline__ void stage_x0(
    int gp0, int tid, const float* __restrict__ xyz,
    const float* __restrict__ pts, const float* __restrict__ pts_t, int use_pt,
    const float* __restrict__ new_xyz, const int* __restrict__ idxo,
    float* __restrict__ bufA)
{
  int pxl = tid >> 2, q = tid & 3;
  int gp = gp0 + pxl;
  int b = gp >> 16;
  int s = (gp >> 5) & (S_ - 1);
  int j = idxo[gp];
  if (use_pt) {
    const float* src = pts_t + ((size_t)b * N_ + j) * 64 + q * 16;
#pragma unroll
    for (int v = 0; v < 4; ++v) {
      float4 f = *(const float4*)(src + v * 4);
      int c = 3 + q * 16 + v * 4;
      bufA[(c + 0) * STR + pxl] = f.x;
      bufA[(c + 1) * STR + pxl] = f.y;
      bufA[(c + 2) * STR + pxl] = f.z;
      bufA[(c + 3) * STR + pxl] = f.w;
    }
  } else {
    const float* src = pts + ((size_t)b * D_ + q * 16) * N_ + j;
#pragma unroll
    for (int v = 0; v < 16; ++v)
      bufA[(3 + q * 16 + v) * STR + pxl] = src[(size_t)v * N_];
  }
  if (q == 0) {
    const float* xb = xyz + (size_t)b * 3 * N_;
    int c3 = (b * S_ + s) * 3;
    bufA[0 * STR + pxl] = xb[j] - new_xyz[c3 + 0];
    bufA[1 * STR + pxl] = xb[N_ + j] - new_xyz[c3 + 1];
    bufA[2 * STR + pxl] = xb[2 * N_ + j] - new_xyz[c3 + 2];
  }
}

// 8-cout conv micro-tile: acc[4 px][8 co] += buf[ci][pg*4..] * w[ci][cog*8..]
template<int CIN, int STR>
__device__ __forceinline__ void conv8(
    const float* __restrict__ buf, const float* __restrict__ wrow, int pg,
    float acc[4][8])
{
  for (int ci = 0; ci < CIN; ++ci) {
    float4 x4 = *(const float4*)&buf[ci * STR + pg * 4];
    float4 wa = *(const float4*)&wrow[ci * 128];
    float4 wb = *(const float4*)&wrow[ci * 128 + 4];
    float xr[4] = {x4.x, x4.y, x4.z, x4.w};
    float wv[8] = {wa.x, wa.y, wa.z, wa.w, wb.x, wb.y, wb.z, wb.w};
#pragma unroll
    for (int i = 0; i < 4; ++i)
#pragma unroll
      for (int j = 0; j < 8; ++j) acc[i][j] = fmaf(xr[i], wv[j], acc[i][j]);
  }
}

// ---------------------------------------------------------------------------
// passA: conv0 stats only (no y0 store).
// ---------------------------------------------------------------------------
__global__ __launch_bounds__(256) void passA_kernel(
    const float* __restrict__ xyz, const float* __restrict__ pts,
    const float* __restrict__ pts_t, int use_pt,
    const float* __restrict__ new_xyz, const int* __restrict__ idxo,
    const float* __restrict__ wt0, const float* __restrict__ b0,
    float* __restrict__ gsum, float* __restrict__ gsq)
{
  __shared__ __align__(16) float bufA[C0_ * 72];
  __shared__ float s_sum[4][128], s_sq[4][128];
  const int tid = threadIdx.x;
  const int lane = tid & 63, wid = tid >> 6;
  const int cog = tid & 15, pg = tid >> 4;
  float bias[8];
#pragma unroll
  for (int j = 0; j < 8; ++j) bias[j] = b0[cog * 8 + j];
  float ssum[8], ssq[8];
#pragma unroll
  for (int j = 0; j < 8; ++j) { ssum[j] = 0.f; ssq[j] = 0.f; }

  for (int t = 0; t < 4; ++t) {
    const int gp0 = (blockIdx.x * 4 + t) * 64;
    __syncthreads();
    stage_x0<72>(gp0, tid, xyz, pts, pts_t, use_pt, new_xyz, idxo, bufA);
    __syncthreads();
    float acc[4][8];
#pragma unroll
    for (int i = 0; i < 4; ++i)
#pragma unroll
      for (int j = 0; j < 8; ++j) acc[i][j] = 0.f;
    conv8<C0_, 72>(bufA, wt0 + cog * 8, pg, acc);
#pragma unroll
    for (int i = 0; i < 4; ++i)
#pragma unroll
      for (int j = 0; j < 8; ++j) {
        float y = acc[i][j] + bias[j];
        ssum[j] += y;
        ssq[j] = fmaf(y, y, ssq[j]);
      }
  }
#pragma unroll
  for (int j = 0; j < 8; ++j) {
    float v = ssum[j];
    v += __shfl_xor(v, 16, 64); v += __shfl_xor(v, 32, 64);
    float q = ssq[j];
    q += __shfl_xor(q, 16, 64); q += __shfl_xor(q, 32, 64);
    if (lane < 16) { s_sum[wid][lane * 8 + j] = v; s_sq[wid][lane * 8 + j] = q; }
  }
  __syncthreads();
  if (tid < 128) {
    float v = s_sum[0][tid] + s_sum[1][tid] + s_sum[2][tid] + s_sum[3][tid];
    float q = s_sq[0][tid] + s_sq[1][tid] + s_sq[2][tid] + s_sq[3][tid];
    atomicAdd(&gsum[tid], v);
    atomicAdd(&gsq[tid], q);
  }
}

// ---------------------------------------------------------------------------
// passB: recompute conv0 -> BN0+ReLU -> conv1 stats (no y1 store).
// ---------------------------------------------------------------------------
__global__ __launch_bounds__(256) void passB_kernel(
    const float* __restrict__ xyz, const float* __restrict__ pts,
    const float* __restrict__ pts_t, int use_pt,
    const float* __restrict__ new_xyz, const int* __restrict__ idxo,
    const float* __restrict__ wt0, const float* __restrict__ b0,
    const float* __restrict__ scale0, const float* __restrict__ shift0,
    const float* __restrict__ wt1, const float* __restrict__ b1,
    float* __restrict__ gsum, float* __restrict__ gsq)
{
  __shared__ __align__(16) float bufA[C0_ * 72];
  __shared__ __align__(16) float bufB[128 * 72];
  __shared__ float s_sum[4][128], s_sq[4][128];
  const int tid = threadIdx.x;
  const int lane = tid & 63, wid = tid >> 6;
  const int cog = tid & 15, pg = tid >> 4;
  float bias0[8], bias1[8], sc0[8], sh0[8];
#pragma unroll
  for (int j = 0; j < 8; ++j) {
    bias0[j] = b0[cog * 8 + j];
    bias1[j] = b1[cog * 8 + j];
    sc0[j] = scale0[cog * 8 + j];
    sh0[j] = shift0[cog * 8 + j];
  }
  float ssum[8], ssq[8];
#pragma unroll
  for (int j = 0; j < 8; ++j) { ssum[j] = 0.f; ssq[j] = 0.f; }

  for (int t = 0; t < 4; ++t) {
    const int gp0 = (blockIdx.x * 4 + t) * 64;
    __syncthreads();
    stage_x0<72>(gp0, tid, xyz, pts, pts_t, use_pt, new_xyz, idxo, bufA);
    __syncthreads();
    float acc[4][8];
#pragma unroll
    for (int i = 0; i < 4; ++i)
#pragma unroll
      for (int j = 0; j < 8; ++j) acc[i][j] = 0.f;
    conv8<C0_, 72>(bufA, wt0 + cog * 8, pg, acc);
#pragma unroll
    for (int i = 0; i < 4; ++i)
#pragma unroll
      for (int j = 0; j < 8; ++j) {
        float y = acc[i][j] + bias0[j];
        bufB[(cog * 8 + j) * 72 + pg * 4 + i] = fmaxf(0.f, fmaf(y, sc0[j], sh0[j]));
      }
    __syncthreads();
#pragma unroll
    for (int i = 0; i < 4; ++i)
#pragma unroll
      for (int j = 0; j < 8; ++j) acc[i][j] = 0.f;
    conv8<128, 72>(bufB, wt1 + cog * 8, pg, acc);
#pragma unroll
    for (int i = 0; i < 4; ++i)
#pragma unroll
      for (int j = 0; j < 8; ++j) {
        float y = acc[i][j] + bias1[j];
        ssum[j] += y;
        ssq[j] = fmaf(y, y, ssq[j]);
      }
  }
#pragma unroll
  for (int j = 0; j < 8; ++j) {
    float v = ssum[j];
    v += __shfl_xor(v, 16, 64); v += __shfl_xor(v, 32, 64);
    float q = ssq[j];
    q += __shfl_xor(q, 16, 64); q += __shfl_xor(q, 32, 64);
    if (lane < 16) { s_sum[wid][lane * 8 + j] = v; s_sq[wid][lane * 8 + j] = q; }
  }
  __syncthreads();
  if (tid < 128) {
    float v = s_sum[0][tid] + s_sum[1][tid] + s_sum[2][tid] + s_sum[3][tid];
    float q = s_sq[0][tid] + s_sq[1][tid] + s_sq[2][tid] + s_sq[3][tid];
    atomicAdd(&gsum[tid], v);
    atomicAdd(&gsq[tid], q);
  }
}

// ---------------------------------------------------------------------------
// passC: recompute conv0->BN0->conv1->BN1->conv2; emit per-centroid max/min
// of y2 (BN2+ReLU is monotone affine) + conv2 stats. Never stores y2.
// R14: LDS cut 90112 -> 79872 B (stride 72->70 on both buffers; s_sum/s_sq
// aliased onto s_m/s_n with an added barrier) => 2 blocks/CU (was 1)
// => 2 waves/SIMD of latency hiding for the gather staging.
// ---------------------------------------------------------------------------
#define STC_ 70
__global__ __launch_bounds__(256) void passC_kernel(
    const float* __restrict__ xyz, const float* __restrict__ pts,
    const float* __restrict__ pts_t, int use_pt,
    const float* __restrict__ new_xyz, const int* __restrict__ idxo,
    const float* __restrict__ wt0, const float* __restrict__ b0,
    const float* __restrict__ scale0, const float* __restrict__ shift0,
    const float* __restrict__ wt1, const float* __restrict__ b1,
    const float* __restrict__ scale1, const float* __restrict__ shift1,
    const float* __restrict__ wt2, const float* __restrict__ b2,
    float* __restrict__ m2max, float* __restrict__ m2min,
    float* __restrict__ gsum, float* __restrict__ gsq)
{
  __shared__ __align__(16) float bufA[128 * STC_];   // x0 (67 rows) then x2 (128 rows)
  __shared__ __align__(16) float bufB[128 * STC_];   // x1
  __shared__ float s_pool[2048];                     // s_m/s_n aliased with s_sum/s_sq
  float* s_m = s_pool;             // [4*256]
  float* s_n = s_pool + 1024;      // [4*256]
  const int tid = threadIdx.x;
  const int lane = tid & 63, wid = tid >> 6;
  const int cog = tid & 15, pg = tid >> 4;
  const int co0 = cog * 16;
  float bias0[8], bias1[8], sc0[8], sh0[8], sc1[8], sh1[8];
#pragma unroll
  for (int j = 0; j < 8; ++j) {
    bias0[j] = b0[cog * 8 + j];
    bias1[j] = b1[cog * 8 + j];
    sc0[j] = scale0[cog * 8 + j];
    sh0[j] = shift0[cog * 8 + j];
    sc1[j] = scale1[cog * 8 + j];
    sh1[j] = shift1[cog * 8 + j];
  }
  float bias2[16];
#pragma unroll
  for (int j = 0; j < 16; ++j) bias2[j] = b2[co0 + j];
  float ssum[16], ssq[16];
#pragma unroll
  for (int j = 0; j < 16; ++j) { ssum[j] = 0.f; ssq[j] = 0.f; }

  for (int t = 0; t < 4; ++t) {
    const int gp0 = (blockIdx.x * 4 + t) * 64;
    __syncthreads();
    stage_x0<STC_>(gp0, tid, xyz, pts, pts_t, use_pt, new_xyz, idxo, bufA);
    __syncthreads();
    // conv0 -> x1
    {
      float acc[4][8];
#pragma unroll
      for (int i = 0; i < 4; ++i)
#pragma unroll
        for (int j = 0; j < 8; ++j) acc[i][j] = 0.f;
      conv8<C0_, STC_>(bufA, wt0 + cog * 8, pg, acc);
#pragma unroll
      for (int i = 0; i < 4; ++i)
#pragma unroll
        for (int j = 0; j < 8; ++j) {
          float y = acc[i][j] + bias0[j];
          bufB[(cog * 8 + j) * STC_ + pg * 4 + i] = fmaxf(0.f, fmaf(y, sc0[j], sh0[j]));
        }
    }
    __syncthreads();                 // all conv0 reads of bufA done
    // conv1 -> x2 (into bufA)
    {
      float acc[4][8];
#pragma unroll
      for (int i = 0; i < 4; ++i)
#pragma unroll
        for (int j = 0; j < 8; ++j) acc[i][j] = 0.f;
      conv8<128, STC_>(bufB, wt1 + cog * 8, pg, acc);
#pragma unroll
      for (int i = 0; i < 4; ++i)
#pragma unroll
        for (int j = 0; j < 8; ++j) {
          float y = acc[i][j] + bias1[j];
          bufA[(cog * 8 + j) * STC_ + pg * 4 + i] = fmaxf(0.f, fmaf(y, sc1[j], sh1[j]));
        }
    }
    __syncthreads();
    // conv2 -> stats + per-centroid max/min
    {
      float acc[4][16];
#pragma unroll
      for (int i = 0; i < 4; ++i)
#pragma unroll
        for (int j = 0; j < 16; ++j) acc[i][j] = 0.f;
      const float* wrow = wt2 + co0;
      for (int ci = 0; ci < 128; ++ci) {
        float4 x4 = *(const float4*)&bufA[ci * STC_ + pg * 4];
        float xr[4] = {x4.x, x4.y, x4.z, x4.w};
        float wv[16];
#pragma unroll
        for (int w4 = 0; w4 < 4; ++w4) {
          float4 wf = *(const float4*)&wrow[ci * 256 + w4 * 4];
          wv[w4 * 4 + 0] = wf.x; wv[w4 * 4 + 1] = wf.y;
          wv[w4 * 4 + 2] = wf.z; wv[w4 * 4 + 3] = wf.w;
        }
#pragma unroll
        for (int i = 0; i < 4; ++i)
#pragma unroll
          for (int j = 0; j < 16; ++j) acc[i][j] = fmaf(xr[i], wv[j], acc[i][j]);
      }
      float mx[16], mn[16];
#pragma unroll
      for (int j = 0; j < 16; ++j) { mx[j] = -3.4e38f; mn[j] = 3.4e38f; }
#pragma unroll
      for (int i = 0; i < 4; ++i)
#pragma unroll
        for (int j = 0; j < 16; ++j) {
          float y = acc[i][j] + bias2[j];
          ssum[j] += y;
          ssq[j] = fmaf(y, y, ssq[j]);
          mx[j] = fmaxf(mx[j], y);
          mn[j] = fminf(mn[j], y);
        }
#pragma unroll
      for (int j = 0; j < 16; ++j) {
        float a = mx[j];
        a = fmaxf(a, __shfl_xor(a, 16, 64)); a = fmaxf(a, __shfl_xor(a, 32, 64));
        float c = mn[j];
        c = fminf(c, __shfl_xor(c, 16, 64)); c = fminf(c, __shfl_xor(c, 32, 64));
        if (lane < 16) {
          s_m[wid * 256 + lane * 16 + j] = a;
          s_n[wid * 256 + lane * 16 + j] = c;
        }
      }
      __syncthreads();
      {
        int co = tid;
        size_t bsA = (size_t)(gp0 >> 5);   // global (b*S+s) of first centroid
        m2max[bsA * 256 + co]       = fmaxf(s_m[co], s_m[256 + co]);
        m2max[(bsA + 1) * 256 + co] = fmaxf(s_m[512 + co], s_m[768 + co]);
        m2min[bsA * 256 + co]       = fminf(s_n[co], s_n[256 + co]);
        m2min[(bsA + 1) * 256 + co] = fminf(s_n[512 + co], s_n[768 + co]);
      }
    }
  }
  __syncthreads();                   // s_m/s_n reads done before s_sum alias reuse
  float* s_sum = s_pool;             // [4][256] aliases s_m/s_n
  float* s_sq  = s_pool + 1024;
#pragma unroll
  for (int j = 0; j < 16; ++j) {
    float v = ssum[j];
    v += __shfl_xor(v, 16, 64); v += __shfl_xor(v, 32, 64);
    float q = ssq[j];
    q += __shfl_xor(q, 16, 64); q += __shfl_xor(q, 32, 64);
    if (lane < 16) { s_sum[wid * 256 + lane * 16 + j] = v; s_sq[wid * 256 + lane * 16 + j] = q; }
  }
  __syncthreads();
  {
    int co = tid;
    float v = s_sum[co] + s_sum[256 + co] + s_sum[512 + co] + s_sum[768 + co];
    float q = s_sq[co] + s_sq[256 + co] + s_sq[512 + co] + s_sq[768 + co];
    atomicAdd(&gsum[co], v);
    atomicAdd(&gsq[co], q);
  }
}

__global__ void stats_kernel(
    const float* __restrict__ gsum, const float* __restrict__ gsq,
    const float* __restrict__ g, const float* __restrict__ be,
    float* __restrict__ scale, float* __restrict__ shift, int C)
{
  int c = threadIdx.x;
  if (c >= C) return;
  const float invP = 1.0f / (float)P_;   // P = 2^18, exact division
  float mean = gsum[c] * invP;
  float var = fmaxf(gsq[c] * invP - mean * mean, 0.f);
  float r = 1.0f / sqrtf(var + 1e-5f);
  float sc = g[c] * r;
  scale[c] = sc;
  shift[c] = be[c] - mean * sc;
}

// feat[b][c][s] = relu(scale2*(scale2>=0 ? max : min) + shift2), transposed.
__global__ __launch_bounds__(256) void final_kernel(
    const float* __restrict__ m2max, const float* __restrict__ m2min,
    const float* __restrict__ scale2, const float* __restrict__ shift2,
    float* __restrict__ d_out)
{
  __shared__ float tmx[64][65], tmn[64][65];
  const int blk = blockIdx.x;
  const int b = blk >> 7;
  const int st = (blk >> 2) & 31;
  const int ct = blk & 3;
  const int s0 = st * 64, c0 = ct * 64;
  const int tx = threadIdx.x & 63, ty = threadIdx.x >> 6;
#pragma unroll
  for (int r = 0; r < 16; ++r) {
    int sl = r * 4 + ty;
    size_t src = ((size_t)(b * S_ + s0 + sl)) * 256 + c0 + tx;
    tmx[sl][tx] = m2max[src];
    tmn[sl][tx] = m2min[src];
  }
  __syncthreads();
#pragma unroll
  for (int r = 0; r < 16; ++r) {
    int cl = r * 4 + ty;
    int c = c0 + cl;
    float sc = scale2[c], sh = shift2[c];
    float m = (sc >= 0.f) ? tmx[tx][cl] : tmn[tx][cl];
    d_out[FEAT_OFF + ((size_t)(b * C3_ + c)) * S_ + s0 + tx] =
        fmaxf(0.f, fmaf(m, sc, sh));
  }
}

// ---------------------------------------------------------------------------
extern "C" void kernel_launch(void* const* d_in, const int* in_sizes, int n_in,
                              void* d_out_v, int out_size, void* d_ws,
                              size_t ws_size, hipStream_t stream)
{
  (void)in_sizes; (void)n_in; (void)out_size;
  const float* xyz = (const float*)d_in[0];
  const float* pts = (const float*)d_in[1];
  const int* seed = (const int*)d_in[2];
  const int* fstart = (const int*)d_in[3];
  const float* W0 = (const float*)d_in[4];
  const float* b0 = (const float*)d_in[5];
  const float* g0 = (const float*)d_in[6];
  const float* be0 = (const float*)d_in[7];
  const float* W1 = (const float*)d_in[8];
  const float* b1 = (const float*)d_in[9];
  const float* g1 = (const float*)d_in[10];
  const float* be1 = (const float*)d_in[11];
  const float* W2 = (const float*)d_in[12];
  const float* b2 = (const float*)d_in[13];
  const float* g2 = (const float*)d_in[14];
  const float* be2 = (const float*)d_in[15];
  float* out = (float*)d_out_v;
  char* ws = (char*)d_ws;

  size_t off = 0;
  auto alloc = [&](size_t bytes) -> void* {
    off = (off + 255) & ~(size_t)255;
    void* p = ws + off;
    off += bytes;
    return p;
  };
  // Compact layout: ~18 MB (+16 MB pts_t only if ws_size allows).
  int*   fps_idx = (int*)alloc((size_t)B_ * S_ * 4);
  float* new_xyz = (float*)alloc((size_t)B_ * S_ * 3 * 4);
  int*   idxo    = (int*)alloc((size_t)B_ * S_ * K_ * 4);
  float* m2max   = (float*)alloc((size_t)B_ * S_ * 256 * 4);
  float* m2min   = (float*)alloc((size_t)B_ * S_ * 256 * 4);
  float* stats   = (float*)alloc(1024 * 4);
  float* scsh    = (float*)alloc(1024 * 4);
  float* wt0     = (float*)alloc((size_t)67 * 128 * 4);
  float* wt1     = (float*)alloc((size_t)128 * 128 * 4);
  float* wt2     = (float*)alloc((size_t)128 * 256 * 4);
  const int use_pt = (ws_size >= (off + (size_t)B_ * N_ * D_ * 4 + (1u << 20))) ? 1 : 0;
  float* pts_t   = use_pt ? (float*)alloc((size_t)B_ * N_ * D_ * 4) : (float*)ws;

  float* gsum0 = stats, *gsq0 = stats + 128;
  float* gsum1 = stats + 256, *gsq1 = stats + 384;
  float* gsum2 = stats + 512, *gsq2 = stats + 768;
  float* scale0 = scsh, *shift0 = scsh + 128;
  float* scale1 = scsh + 256, *shift1 = scsh + 384;
  float* scale2 = scsh + 512, *shift2 = scsh + 768;

  hipMemsetAsync(stats, 0, 1024 * 4, stream);
  transpose_w_kernel<<<226, 256, 0, stream>>>(W0, W1, W2, wt0, wt1, wt2);
  if (use_pt)
    transpose_pts_kernel<<<B_ * 256, 256, 0, stream>>>(pts, pts_t);
  fps_kernel<<<B_, 512, 0, stream>>>(xyz, fstart, fps_idx);
  gather_kernel<<<(B_ * S_ + 255) / 256, 256, 0, stream>>>(xyz, seed, fps_idx,
                                                           new_xyz, out);
  ballquery_kernel<<<B_ * S_ / 4, 256, 0, stream>>>(xyz, new_xyz, idxo);
  passA_kernel<<<1024, 256, 0, stream>>>(xyz, pts, pts_t, use_pt, new_xyz, idxo,
                                         wt0, b0, gsum0, gsq0);
  stats_kernel<<<1, 128, 0, stream>>>(gsum0, gsq0, g0, be0, scale0, shift0, 128);
  passB_kernel<<<1024, 256, 0, stream>>>(xyz, pts, pts_t, use_pt, new_xyz, idxo,
                                         wt0, b0, scale0, shift0, wt1, b1,
                                         gsum1, gsq1);
  stats_kernel<<<1, 128, 0, stream>>>(gsum1, gsq1, g1, be1, scale1, shift1, 128);
  passC_kernel<<<1024, 256, 0, stream>>>(xyz, pts, pts_t, use_pt, new_xyz, idxo,
                                         wt0, b0, scale0, shift0, wt1, b1,
                                         scale1, shift1, wt2, b2,
                                         m2max, m2min, gsum2, gsq2);
  stats_kernel<<<1, 256, 0, stream>>>(gsum2, gsq2, g2, be2, scale2, shift2, 256);
  final_kernel<<<512, 256, 0, stream>>>(m2max, m2min, scale2, shift2, out);
}